// Round 1
// baseline (2832.055 us; speedup 1.0000x reference)
//
#include <hip/hip_runtime.h>
#include <cmath>

constexpr int NN   = 100000;
constexpr int NE   = 3200000;
constexpr int DIN  = 128;
constexpr int DH   = 32;
constexpr int DOUT = 20;

// ---------------- layer-1 projections: xl = x@W1l, xr = x@W1r ----------------
__global__ __launch_bounds__(256) void lin1_kernel(
    const float* __restrict__ x, const float* __restrict__ Wl,
    const float* __restrict__ Wr, float* __restrict__ xl, float* __restrict__ xr)
{
    int node = blockIdx.x * 256 + threadIdx.x;
    if (node >= NN) return;
    float accl[DH], accr[DH];
#pragma unroll
    for (int j = 0; j < DH; ++j) { accl[j] = 0.f; accr[j] = 0.f; }
    const float4* xrow = reinterpret_cast<const float4*>(x + (size_t)node * DIN);
    for (int k0 = 0; k0 < DIN; k0 += 4) {
        float4 xv = xrow[k0 >> 2];
        float xs[4] = {xv.x, xv.y, xv.z, xv.w};
#pragma unroll
        for (int kk = 0; kk < 4; ++kk) {
            float xk = xs[kk];
            const float* wl = Wl + (k0 + kk) * DH;
            const float* wr = Wr + (k0 + kk) * DH;
#pragma unroll
            for (int j = 0; j < DH; ++j) {
                accl[j] = fmaf(xk, wl[j], accl[j]);
                accr[j] = fmaf(xk, wr[j], accr[j]);
            }
        }
    }
    float4* xl4 = reinterpret_cast<float4*>(xl + (size_t)node * DH);
    float4* xr4 = reinterpret_cast<float4*>(xr + (size_t)node * DH);
#pragma unroll
    for (int q = 0; q < DH / 4; ++q) {
        xl4[q] = make_float4(accl[q*4+0], accl[q*4+1], accl[q*4+2], accl[q*4+3]);
        xr4[q] = make_float4(accr[q*4+0], accr[q*4+1], accr[q*4+2], accr[q*4+3]);
    }
}

// ---------------- edge aggregation: agg[dst] += feat[src] (+cnt) ----------------
template<bool DO_CNT>
__global__ __launch_bounds__(256) void agg_kernel(
    const int* __restrict__ ei, const float* __restrict__ feat,
    float* __restrict__ agg, float* __restrict__ cnt)
{
    int tid = blockIdx.x * 256 + threadIdx.x;
    int e = tid >> 3;          // 8 threads per edge
    int c = tid & 7;           // which float4 chunk of the 32-dim row
    if (e >= NE) return;
    int src = ei[e];
    int dst = ei[NE + e];
    float4 v = reinterpret_cast<const float4*>(feat)[(size_t)src * 8 + c];
    float* base = agg + (size_t)dst * DH + c * 4;
    atomicAdd(base + 0, v.x);
    atomicAdd(base + 1, v.y);
    atomicAdd(base + 2, v.z);
    atomicAdd(base + 3, v.w);
    if (DO_CNT && c == 0) atomicAdd(cnt + dst, 1.0f);
}

// ---- post layer1: o = agg/cnt + b1 + xr; h1 = tanh(l2norm(o)); fused lin2 ----
__global__ __launch_bounds__(256) void post1_kernel(
    const float* __restrict__ agg, const float* __restrict__ cnt,
    const float* __restrict__ xr, const float* __restrict__ b1,
    const float* __restrict__ W2l, const float* __restrict__ W2r,
    float* __restrict__ hl, float* __restrict__ hr)
{
    int node = blockIdx.x * 256 + threadIdx.x;
    if (node >= NN) return;
    float inv = 1.0f / fmaxf(cnt[node], 1.0f);
    float o[DH];
    const float4* ag4 = reinterpret_cast<const float4*>(agg + (size_t)node * DH);
    const float4* xr4 = reinterpret_cast<const float4*>(xr  + (size_t)node * DH);
#pragma unroll
    for (int q = 0; q < DH / 4; ++q) {
        float4 a = ag4[q]; float4 r = xr4[q];
        o[q*4+0] = fmaf(a.x, inv, b1[q*4+0] + r.x);
        o[q*4+1] = fmaf(a.y, inv, b1[q*4+1] + r.y);
        o[q*4+2] = fmaf(a.z, inv, b1[q*4+2] + r.z);
        o[q*4+3] = fmaf(a.w, inv, b1[q*4+3] + r.w);
    }
    float ss = 0.f;
#pragma unroll
    for (int j = 0; j < DH; ++j) ss += o[j] * o[j];
    float rn = 1.0f / fmaxf(sqrtf(ss), 1e-12f);
    float h[DH];
#pragma unroll
    for (int j = 0; j < DH; ++j) h[j] = tanhf(o[j] * rn);

    // fused layer-2 projections: hl = h1@W2l, hr = h1@W2r
    float al[DH], ar[DH];
#pragma unroll
    for (int j = 0; j < DH; ++j) { al[j] = 0.f; ar[j] = 0.f; }
    for (int k = 0; k < DH; ++k) {
        float hk = h[k];
        const float* wl = W2l + k * DH;
        const float* wr = W2r + k * DH;
#pragma unroll
        for (int j = 0; j < DH; ++j) {
            al[j] = fmaf(hk, wl[j], al[j]);
            ar[j] = fmaf(hk, wr[j], ar[j]);
        }
    }
    float4* hl4 = reinterpret_cast<float4*>(hl + (size_t)node * DH);
    float4* hr4 = reinterpret_cast<float4*>(hr + (size_t)node * DH);
#pragma unroll
    for (int q = 0; q < DH / 4; ++q) {
        hl4[q] = make_float4(al[q*4+0], al[q*4+1], al[q*4+2], al[q*4+3]);
        hr4[q] = make_float4(ar[q*4+0], ar[q*4+1], ar[q*4+2], ar[q*4+3]);
    }
}

// ---- post layer2 + classifier: h2 = tanh(l2norm(agg/cnt + b2 + hr));
//      out = log_softmax(h2@Wc + bc) ----
__global__ __launch_bounds__(256) void post2_kernel(
    const float* __restrict__ agg, const float* __restrict__ cnt,
    const float* __restrict__ hr, const float* __restrict__ b2,
    const float* __restrict__ Wc, const float* __restrict__ bc,
    float* __restrict__ h2out, float* __restrict__ outp)
{
    int node = blockIdx.x * 256 + threadIdx.x;
    if (node >= NN) return;
    float inv = 1.0f / fmaxf(cnt[node], 1.0f);
    float o[DH];
    const float4* ag4 = reinterpret_cast<const float4*>(agg + (size_t)node * DH);
    const float4* hr4 = reinterpret_cast<const float4*>(hr  + (size_t)node * DH);
#pragma unroll
    for (int q = 0; q < DH / 4; ++q) {
        float4 a = ag4[q]; float4 r = hr4[q];
        o[q*4+0] = fmaf(a.x, inv, b2[q*4+0] + r.x);
        o[q*4+1] = fmaf(a.y, inv, b2[q*4+1] + r.y);
        o[q*4+2] = fmaf(a.z, inv, b2[q*4+2] + r.z);
        o[q*4+3] = fmaf(a.w, inv, b2[q*4+3] + r.w);
    }
    float ss = 0.f;
#pragma unroll
    for (int j = 0; j < DH; ++j) ss += o[j] * o[j];
    float rn = 1.0f / fmaxf(sqrtf(ss), 1e-12f);
    float h[DH];
#pragma unroll
    for (int j = 0; j < DH; ++j) h[j] = tanhf(o[j] * rn);

    float4* h2o = reinterpret_cast<float4*>(h2out + (size_t)node * DH);
#pragma unroll
    for (int q = 0; q < DH / 4; ++q)
        h2o[q] = make_float4(h[q*4+0], h[q*4+1], h[q*4+2], h[q*4+3]);

    // classifier
    float z[DOUT];
#pragma unroll
    for (int t = 0; t < DOUT; ++t) z[t] = bc[t];
    for (int k = 0; k < DH; ++k) {
        float hk = h[k];
        const float* wc = Wc + k * DOUT;
#pragma unroll
        for (int t = 0; t < DOUT; ++t) z[t] = fmaf(hk, wc[t], z[t]);
    }
    float m = -INFINITY;
#pragma unroll
    for (int t = 0; t < DOUT; ++t) m = fmaxf(m, z[t]);
    float s = 0.f;
#pragma unroll
    for (int t = 0; t < DOUT; ++t) s += expf(z[t] - m);
    float lse = m + logf(s);
    float* orow = outp + (size_t)node * DOUT;
#pragma unroll
    for (int t = 0; t < DOUT; ++t) orow[t] = z[t] - lse;
}

extern "C" void kernel_launch(void* const* d_in, const int* in_sizes, int n_in,
                              void* d_out, int out_size, void* d_ws, size_t ws_size,
                              hipStream_t stream) {
    const float* x   = (const float*)d_in[0];
    const int*   ei  = (const int*)d_in[1];
    const float* W1l = (const float*)d_in[2];
    const float* b1  = (const float*)d_in[3];
    const float* W1r = (const float*)d_in[4];
    const float* W2l = (const float*)d_in[5];
    const float* b2  = (const float*)d_in[6];
    const float* W2r = (const float*)d_in[7];
    const float* Wc  = (const float*)d_in[8];
    const float* bc  = (const float*)d_in[9];

    float* outp = (float*)d_out;                         // [NN, 20]
    float* hout = outp + (size_t)NN * DOUT;              // [NN, 32]

    float* xl  = (float*)d_ws;                           // NN*32
    float* xr  = xl + (size_t)NN * DH;                   // NN*32
    float* agg = xr + (size_t)NN * DH;                   // NN*32
    float* cnt = agg + (size_t)NN * DH;                  // NN   (contiguous after agg)

    const int nodeBlocks = (NN + 255) / 256;
    const int edgeBlocks = (NE * 8) / 256;               // 100000

    // zero agg + cnt (contiguous) for layer 1
    hipMemsetAsync(agg, 0, (size_t)NN * (DH + 1) * sizeof(float), stream);

    lin1_kernel<<<nodeBlocks, 256, 0, stream>>>(x, W1l, W1r, xl, xr);
    agg_kernel<true><<<edgeBlocks, 256, 0, stream>>>(ei, xl, agg, cnt);
    post1_kernel<<<nodeBlocks, 256, 0, stream>>>(agg, cnt, xr, b1, W2l, W2r, xl, xr);

    // re-zero agg for layer 2
    hipMemsetAsync(agg, 0, (size_t)NN * DH * sizeof(float), stream);

    agg_kernel<false><<<edgeBlocks, 256, 0, stream>>>(ei, xl, agg, nullptr);
    post2_kernel<<<nodeBlocks, 256, 0, stream>>>(agg, cnt, xr, b2, Wc, bc, hout, outp);
}

// Round 2
// 627.627 us; speedup vs baseline: 4.5123x; 4.5123x over previous
//
#include <hip/hip_runtime.h>
#include <cmath>

constexpr int NN   = 100000;
constexpr int NE   = 3200000;
constexpr int DIN  = 128;
constexpr int DH   = 32;
constexpr int DOUT = 20;

constexpr int SCAN_THREADS = 256;
constexpr int SCAN_PER_THREAD = 16;
constexpr int SCAN_CHUNK = SCAN_THREADS * SCAN_PER_THREAD;   // 4096
constexpr int N_CHUNKS = (NN + SCAN_CHUNK - 1) / SCAN_CHUNK; // 25

// ---------------- layer-1 projections: xl = x@W1l, xr = x@W1r ----------------
__global__ __launch_bounds__(256) void lin1_kernel(
    const float* __restrict__ x, const float* __restrict__ Wl,
    const float* __restrict__ Wr, float* __restrict__ xl, float* __restrict__ xr)
{
    int node = blockIdx.x * 256 + threadIdx.x;
    if (node >= NN) return;
    float accl[DH], accr[DH];
#pragma unroll
    for (int j = 0; j < DH; ++j) { accl[j] = 0.f; accr[j] = 0.f; }
    const float4* xrow = reinterpret_cast<const float4*>(x + (size_t)node * DIN);
    for (int k0 = 0; k0 < DIN; k0 += 4) {
        float4 xv = xrow[k0 >> 2];
        float xs[4] = {xv.x, xv.y, xv.z, xv.w};
#pragma unroll
        for (int kk = 0; kk < 4; ++kk) {
            float xk = xs[kk];
            const float* wl = Wl + (k0 + kk) * DH;
            const float* wr = Wr + (k0 + kk) * DH;
#pragma unroll
            for (int j = 0; j < DH; ++j) {
                accl[j] = fmaf(xk, wl[j], accl[j]);
                accr[j] = fmaf(xk, wr[j], accr[j]);
            }
        }
    }
    float4* xl4 = reinterpret_cast<float4*>(xl + (size_t)node * DH);
    float4* xr4 = reinterpret_cast<float4*>(xr + (size_t)node * DH);
#pragma unroll
    for (int q = 0; q < DH / 4; ++q) {
        xl4[q] = make_float4(accl[q*4+0], accl[q*4+1], accl[q*4+2], accl[q*4+3]);
        xr4[q] = make_float4(accr[q*4+0], accr[q*4+1], accr[q*4+2], accr[q*4+3]);
    }
}

// ---------------- CSR build: histogram of dst ----------------
__global__ __launch_bounds__(256) void hist_kernel(
    const int* __restrict__ ei, int* __restrict__ deg)
{
    int e = blockIdx.x * 256 + threadIdx.x;
    if (e >= NE) return;
    atomicAdd(&deg[ei[NE + e]], 1);
}

// ---------------- scan step 1: per-chunk sums ----------------
__global__ __launch_bounds__(SCAN_THREADS) void scan_partial(
    const int* __restrict__ deg, int* __restrict__ chunkSums)
{
    __shared__ int sdata[SCAN_THREADS];
    int b = blockIdx.x, t = threadIdx.x;
    int base = b * SCAN_CHUNK + t * SCAN_PER_THREAD;
    int s = 0;
#pragma unroll
    for (int i = 0; i < SCAN_PER_THREAD; ++i) {
        int idx = base + i;
        if (idx < NN) s += deg[idx];
    }
    sdata[t] = s;
    __syncthreads();
    for (int off = SCAN_THREADS / 2; off > 0; off >>= 1) {
        if (t < off) sdata[t] += sdata[t + off];
        __syncthreads();
    }
    if (t == 0) chunkSums[b] = sdata[0];
}

// ---------------- scan step 2: exclusive scan of chunk sums (tiny) ----------------
__global__ void scan_offsets(const int* __restrict__ chunkSums, int* __restrict__ chunkOffs)
{
    if (threadIdx.x == 0 && blockIdx.x == 0) {
        int acc = 0;
        for (int i = 0; i < N_CHUNKS; ++i) { chunkOffs[i] = acc; acc += chunkSums[i]; }
    }
}

// ---------------- scan step 3: final exclusive scan, write start & ptr ----------------
__global__ __launch_bounds__(SCAN_THREADS) void scan_final(
    const int* __restrict__ deg, const int* __restrict__ chunkOffs,
    int* __restrict__ start, int* __restrict__ ptr)
{
    __shared__ int sdata[SCAN_THREADS];
    int b = blockIdx.x, t = threadIdx.x;
    int base = b * SCAN_CHUNK + t * SCAN_PER_THREAD;
    int local[SCAN_PER_THREAD];
    int s = 0;
#pragma unroll
    for (int i = 0; i < SCAN_PER_THREAD; ++i) {
        int idx = base + i;
        int d = (idx < NN) ? deg[idx] : 0;
        local[i] = s;
        s += d;
    }
    sdata[t] = s;
    __syncthreads();
    // Hillis-Steele inclusive scan over 256 thread totals
    for (int off = 1; off < SCAN_THREADS; off <<= 1) {
        int tmp = (t >= off) ? sdata[t - off] : 0;
        __syncthreads();
        sdata[t] += tmp;
        __syncthreads();
    }
    int excl = sdata[t] - s;                 // exclusive prefix of this thread
    int offset = chunkOffs[b] + excl;
#pragma unroll
    for (int i = 0; i < SCAN_PER_THREAD; ++i) {
        int idx = base + i;
        if (idx < NN) {
            int v = offset + local[i];
            start[idx] = v;
            ptr[idx]   = v;
        }
    }
}

// ---------------- scatter edges into CSR slots ----------------
__global__ __launch_bounds__(256) void scatter_kernel(
    const int* __restrict__ ei, int* __restrict__ ptr, int* __restrict__ csrsrc)
{
    int e = blockIdx.x * 256 + threadIdx.x;
    if (e >= NE) return;
    int src = ei[e];
    int dst = ei[NE + e];
    int pos = atomicAdd(&ptr[dst], 1);
    csrsrc[pos] = src;
}

// ---------------- gather aggregation: agg[g] = sum over neighbors ----------------
__global__ __launch_bounds__(256) void gather_kernel(
    const int* __restrict__ start, const int* __restrict__ deg,
    const int* __restrict__ csrsrc, const float* __restrict__ feat,
    float* __restrict__ agg)
{
    int tid = blockIdx.x * 256 + threadIdx.x;
    int g = tid >> 3;            // node
    int c = tid & 7;             // float4 chunk of the 32-dim row
    if (g >= NN) return;
    int s = start[g];
    int e = s + deg[g];
    const float4* f4 = reinterpret_cast<const float4*>(feat);
    float4 a0 = make_float4(0.f, 0.f, 0.f, 0.f);
    float4 a1 = make_float4(0.f, 0.f, 0.f, 0.f);
    int i = s;
    for (; i + 2 <= e; i += 2) {
        int s0 = csrsrc[i];
        int s1 = csrsrc[i + 1];
        float4 v0 = f4[(size_t)s0 * 8 + c];
        float4 v1 = f4[(size_t)s1 * 8 + c];
        a0.x += v0.x; a0.y += v0.y; a0.z += v0.z; a0.w += v0.w;
        a1.x += v1.x; a1.y += v1.y; a1.z += v1.z; a1.w += v1.w;
    }
    if (i < e) {
        int s0 = csrsrc[i];
        float4 v0 = f4[(size_t)s0 * 8 + c];
        a0.x += v0.x; a0.y += v0.y; a0.z += v0.z; a0.w += v0.w;
    }
    a0.x += a1.x; a0.y += a1.y; a0.z += a1.z; a0.w += a1.w;
    reinterpret_cast<float4*>(agg)[(size_t)g * 8 + c] = a0;
}

// ---- post layer1: o = agg/deg + b1 + xr; h1 = tanh(l2norm(o)); fused lin2 ----
__global__ __launch_bounds__(256) void post1_kernel(
    const float* __restrict__ agg, const int* __restrict__ deg,
    const float* __restrict__ xr, const float* __restrict__ b1,
    const float* __restrict__ W2l, const float* __restrict__ W2r,
    float* __restrict__ hl, float* __restrict__ hr)
{
    int node = blockIdx.x * 256 + threadIdx.x;
    if (node >= NN) return;
    float inv = 1.0f / fmaxf((float)deg[node], 1.0f);
    float o[DH];
    const float4* ag4 = reinterpret_cast<const float4*>(agg + (size_t)node * DH);
    const float4* xr4 = reinterpret_cast<const float4*>(xr  + (size_t)node * DH);
#pragma unroll
    for (int q = 0; q < DH / 4; ++q) {
        float4 a = ag4[q]; float4 r = xr4[q];
        o[q*4+0] = fmaf(a.x, inv, b1[q*4+0] + r.x);
        o[q*4+1] = fmaf(a.y, inv, b1[q*4+1] + r.y);
        o[q*4+2] = fmaf(a.z, inv, b1[q*4+2] + r.z);
        o[q*4+3] = fmaf(a.w, inv, b1[q*4+3] + r.w);
    }
    float ss = 0.f;
#pragma unroll
    for (int j = 0; j < DH; ++j) ss += o[j] * o[j];
    float rn = 1.0f / fmaxf(sqrtf(ss), 1e-12f);
    float h[DH];
#pragma unroll
    for (int j = 0; j < DH; ++j) h[j] = tanhf(o[j] * rn);

    float al[DH], ar[DH];
#pragma unroll
    for (int j = 0; j < DH; ++j) { al[j] = 0.f; ar[j] = 0.f; }
    for (int k = 0; k < DH; ++k) {
        float hk = h[k];
        const float* wl = W2l + k * DH;
        const float* wr = W2r + k * DH;
#pragma unroll
        for (int j = 0; j < DH; ++j) {
            al[j] = fmaf(hk, wl[j], al[j]);
            ar[j] = fmaf(hk, wr[j], ar[j]);
        }
    }
    float4* hl4 = reinterpret_cast<float4*>(hl + (size_t)node * DH);
    float4* hr4 = reinterpret_cast<float4*>(hr + (size_t)node * DH);
#pragma unroll
    for (int q = 0; q < DH / 4; ++q) {
        hl4[q] = make_float4(al[q*4+0], al[q*4+1], al[q*4+2], al[q*4+3]);
        hr4[q] = make_float4(ar[q*4+0], ar[q*4+1], ar[q*4+2], ar[q*4+3]);
    }
}

// ---- post layer2 + classifier ----
__global__ __launch_bounds__(256) void post2_kernel(
    const float* __restrict__ agg, const int* __restrict__ deg,
    const float* __restrict__ hr, const float* __restrict__ b2,
    const float* __restrict__ Wc, const float* __restrict__ bc,
    float* __restrict__ h2out, float* __restrict__ outp)
{
    int node = blockIdx.x * 256 + threadIdx.x;
    if (node >= NN) return;
    float inv = 1.0f / fmaxf((float)deg[node], 1.0f);
    float o[DH];
    const float4* ag4 = reinterpret_cast<const float4*>(agg + (size_t)node * DH);
    const float4* hr4 = reinterpret_cast<const float4*>(hr  + (size_t)node * DH);
#pragma unroll
    for (int q = 0; q < DH / 4; ++q) {
        float4 a = ag4[q]; float4 r = hr4[q];
        o[q*4+0] = fmaf(a.x, inv, b2[q*4+0] + r.x);
        o[q*4+1] = fmaf(a.y, inv, b2[q*4+1] + r.y);
        o[q*4+2] = fmaf(a.z, inv, b2[q*4+2] + r.z);
        o[q*4+3] = fmaf(a.w, inv, b2[q*4+3] + r.w);
    }
    float ss = 0.f;
#pragma unroll
    for (int j = 0; j < DH; ++j) ss += o[j] * o[j];
    float rn = 1.0f / fmaxf(sqrtf(ss), 1e-12f);
    float h[DH];
#pragma unroll
    for (int j = 0; j < DH; ++j) h[j] = tanhf(o[j] * rn);

    float4* h2o = reinterpret_cast<float4*>(h2out + (size_t)node * DH);
#pragma unroll
    for (int q = 0; q < DH / 4; ++q)
        h2o[q] = make_float4(h[q*4+0], h[q*4+1], h[q*4+2], h[q*4+3]);

    float z[DOUT];
#pragma unroll
    for (int t = 0; t < DOUT; ++t) z[t] = bc[t];
    for (int k = 0; k < DH; ++k) {
        float hk = h[k];
        const float* wc = Wc + k * DOUT;
#pragma unroll
        for (int t = 0; t < DOUT; ++t) z[t] = fmaf(hk, wc[t], z[t]);
    }
    float m = -INFINITY;
#pragma unroll
    for (int t = 0; t < DOUT; ++t) m = fmaxf(m, z[t]);
    float s = 0.f;
#pragma unroll
    for (int t = 0; t < DOUT; ++t) s += expf(z[t] - m);
    float lse = m + logf(s);
    float* orow = outp + (size_t)node * DOUT;
#pragma unroll
    for (int t = 0; t < DOUT; ++t) orow[t] = z[t] - lse;
}

extern "C" void kernel_launch(void* const* d_in, const int* in_sizes, int n_in,
                              void* d_out, int out_size, void* d_ws, size_t ws_size,
                              hipStream_t stream) {
    const float* x   = (const float*)d_in[0];
    const int*   ei  = (const int*)d_in[1];
    const float* W1l = (const float*)d_in[2];
    const float* b1  = (const float*)d_in[3];
    const float* W1r = (const float*)d_in[4];
    const float* W2l = (const float*)d_in[5];
    const float* b2  = (const float*)d_in[6];
    const float* W2r = (const float*)d_in[7];
    const float* Wc  = (const float*)d_in[8];
    const float* bc  = (const float*)d_in[9];

    float* outp = (float*)d_out;                          // [NN, 20]
    float* hout = outp + (size_t)NN * DOUT;               // [NN, 32]

    // workspace layout
    float* xl   = (float*)d_ws;                           // NN*DH
    float* xr   = xl + (size_t)NN * DH;                   // NN*DH
    float* agg  = xr + (size_t)NN * DH;                   // NN*DH
    int* deg    = (int*)(agg + (size_t)NN * DH);          // NN
    int* start  = deg + NN;                               // NN
    int* ptr    = start + NN;                             // NN
    int* chunkSums = ptr + NN;                            // N_CHUNKS
    int* chunkOffs = chunkSums + N_CHUNKS;                // N_CHUNKS
    int* csrsrc = chunkOffs + N_CHUNKS;                   // NE

    const int nodeBlocks  = (NN + 255) / 256;
    const int edgeBlocks  = (NE + 255) / 256;
    const int groupBlocks = (NN * 8 + 255) / 256;

    hipMemsetAsync(deg, 0, (size_t)NN * sizeof(int), stream);

    lin1_kernel<<<nodeBlocks, 256, 0, stream>>>(x, W1l, W1r, xl, xr);
    hist_kernel<<<edgeBlocks, 256, 0, stream>>>(ei, deg);
    scan_partial<<<N_CHUNKS, SCAN_THREADS, 0, stream>>>(deg, chunkSums);
    scan_offsets<<<1, 64, 0, stream>>>(chunkSums, chunkOffs);
    scan_final<<<N_CHUNKS, SCAN_THREADS, 0, stream>>>(deg, chunkOffs, start, ptr);
    scatter_kernel<<<edgeBlocks, 256, 0, stream>>>(ei, ptr, csrsrc);

    gather_kernel<<<groupBlocks, 256, 0, stream>>>(start, deg, csrsrc, xl, agg);
    post1_kernel<<<nodeBlocks, 256, 0, stream>>>(agg, deg, xr, b1, W2l, W2r, xl, xr);

    gather_kernel<<<groupBlocks, 256, 0, stream>>>(start, deg, csrsrc, xl, agg);
    post2_kernel<<<nodeBlocks, 256, 0, stream>>>(agg, deg, xr, b2, Wc, bc, hout, outp);
}

// Round 3
// 549.414 us; speedup vs baseline: 5.1547x; 1.1424x over previous
//
#include <hip/hip_runtime.h>
#include <cmath>

constexpr int NN   = 100000;
constexpr int NE   = 3200000;
constexpr int DIN  = 128;
constexpr int DH   = 32;
constexpr int DOUT = 20;

constexpr int SCAN_THREADS = 256;
constexpr int SCAN_PER_THREAD = 16;
constexpr int SCAN_CHUNK = SCAN_THREADS * SCAN_PER_THREAD;   // 4096
constexpr int N_CHUNKS = (NN + SCAN_CHUNK - 1) / SCAN_CHUNK; // 25

constexpr int N_PASSES = 8;
constexpr int PASS_RANGE = (NN + N_PASSES - 1) / N_PASSES;   // 12500

// ---------------- layer-1 projections: xl = x@W1l, xr = x@W1r ----------------
__global__ __launch_bounds__(256) void lin1_kernel(
    const float* __restrict__ x, const float* __restrict__ Wl,
    const float* __restrict__ Wr, float* __restrict__ xl, float* __restrict__ xr)
{
    int node = blockIdx.x * 256 + threadIdx.x;
    if (node >= NN) return;
    float accl[DH], accr[DH];
#pragma unroll
    for (int j = 0; j < DH; ++j) { accl[j] = 0.f; accr[j] = 0.f; }
    const float4* xrow = reinterpret_cast<const float4*>(x + (size_t)node * DIN);
    for (int k0 = 0; k0 < DIN; k0 += 4) {
        float4 xv = xrow[k0 >> 2];
        float xs[4] = {xv.x, xv.y, xv.z, xv.w};
#pragma unroll
        for (int kk = 0; kk < 4; ++kk) {
            float xk = xs[kk];
            const float* wl = Wl + (k0 + kk) * DH;
            const float* wr = Wr + (k0 + kk) * DH;
#pragma unroll
            for (int j = 0; j < DH; ++j) {
                accl[j] = fmaf(xk, wl[j], accl[j]);
                accr[j] = fmaf(xk, wr[j], accr[j]);
            }
        }
    }
    float4* xl4 = reinterpret_cast<float4*>(xl + (size_t)node * DH);
    float4* xr4 = reinterpret_cast<float4*>(xr + (size_t)node * DH);
#pragma unroll
    for (int q = 0; q < DH / 4; ++q) {
        xl4[q] = make_float4(accl[q*4+0], accl[q*4+1], accl[q*4+2], accl[q*4+3]);
        xr4[q] = make_float4(accr[q*4+0], accr[q*4+1], accr[q*4+2], accr[q*4+3]);
    }
}

// ---------------- CSR build: histogram of dst ----------------
__global__ __launch_bounds__(256) void hist_kernel(
    const int* __restrict__ ei, int* __restrict__ deg)
{
    int e = blockIdx.x * 256 + threadIdx.x;
    if (e >= NE) return;
    atomicAdd(&deg[ei[NE + e]], 1);
}

// ---------------- scan step 1: per-chunk sums ----------------
__global__ __launch_bounds__(SCAN_THREADS) void scan_partial(
    const int* __restrict__ deg, int* __restrict__ chunkSums)
{
    __shared__ int sdata[SCAN_THREADS];
    int b = blockIdx.x, t = threadIdx.x;
    int base = b * SCAN_CHUNK + t * SCAN_PER_THREAD;
    int s = 0;
#pragma unroll
    for (int i = 0; i < SCAN_PER_THREAD; ++i) {
        int idx = base + i;
        if (idx < NN) s += deg[idx];
    }
    sdata[t] = s;
    __syncthreads();
    for (int off = SCAN_THREADS / 2; off > 0; off >>= 1) {
        if (t < off) sdata[t] += sdata[t + off];
        __syncthreads();
    }
    if (t == 0) chunkSums[b] = sdata[0];
}

// ---------------- scan step 2: exclusive scan of chunk sums (tiny) ----------------
__global__ void scan_offsets(const int* __restrict__ chunkSums, int* __restrict__ chunkOffs)
{
    if (threadIdx.x == 0 && blockIdx.x == 0) {
        int acc = 0;
        for (int i = 0; i < N_CHUNKS; ++i) { chunkOffs[i] = acc; acc += chunkSums[i]; }
    }
}

// ---------------- scan step 3: final exclusive scan, write start & ptr ----------------
__global__ __launch_bounds__(SCAN_THREADS) void scan_final(
    const int* __restrict__ deg, const int* __restrict__ chunkOffs,
    int* __restrict__ start, int* __restrict__ ptr)
{
    __shared__ int sdata[SCAN_THREADS];
    int b = blockIdx.x, t = threadIdx.x;
    int base = b * SCAN_CHUNK + t * SCAN_PER_THREAD;
    int local[SCAN_PER_THREAD];
    int s = 0;
#pragma unroll
    for (int i = 0; i < SCAN_PER_THREAD; ++i) {
        int idx = base + i;
        int d = (idx < NN) ? deg[idx] : 0;
        local[i] = s;
        s += d;
    }
    sdata[t] = s;
    __syncthreads();
    for (int off = 1; off < SCAN_THREADS; off <<= 1) {
        int tmp = (t >= off) ? sdata[t - off] : 0;
        __syncthreads();
        sdata[t] += tmp;
        __syncthreads();
    }
    int excl = sdata[t] - s;
    int offset = chunkOffs[b] + excl;
#pragma unroll
    for (int i = 0; i < SCAN_PER_THREAD; ++i) {
        int idx = base + i;
        if (idx < NN) {
            int v = offset + local[i];
            start[idx] = v;
            ptr[idx]   = v;
        }
    }
}

// ------- scatter pass: only edges whose dst is in [lo,hi) -> contiguous CSR region -------
__global__ __launch_bounds__(256) void scatter_pass_kernel(
    const int* __restrict__ ei, int* __restrict__ ptr, int* __restrict__ csrsrc,
    int lo, int hi)
{
    int t = blockIdx.x * 256 + threadIdx.x;
    int e0 = t * 4;
    if (e0 >= NE) return;
    int4 d4 = *reinterpret_cast<const int4*>(ei + NE + e0);
    int4 s4 = *reinterpret_cast<const int4*>(ei + e0);
    int ds[4] = {d4.x, d4.y, d4.z, d4.w};
    int ss[4] = {s4.x, s4.y, s4.z, s4.w};
#pragma unroll
    for (int k = 0; k < 4; ++k) {
        int dst = ds[k];
        if (dst >= lo && dst < hi) {
            int pos = atomicAdd(&ptr[dst], 1);
            csrsrc[pos] = ss[k];
        }
    }
}

// ---------------- gather aggregation: agg[g] = sum over neighbors ----------------
__global__ __launch_bounds__(256) void gather_kernel(
    const int* __restrict__ start, const int* __restrict__ deg,
    const int* __restrict__ csrsrc, const float* __restrict__ feat,
    float* __restrict__ agg)
{
    int tid = blockIdx.x * 256 + threadIdx.x;
    int g = tid >> 3;            // node
    int c = tid & 7;             // float4 chunk of the 32-dim row
    if (g >= NN) return;
    int s = start[g];
    int e = s + deg[g];
    const float4* f4 = reinterpret_cast<const float4*>(feat);
    float4 a0 = make_float4(0.f, 0.f, 0.f, 0.f);
    float4 a1 = make_float4(0.f, 0.f, 0.f, 0.f);
    int i = s;
    for (; i + 2 <= e; i += 2) {
        int s0 = csrsrc[i];
        int s1 = csrsrc[i + 1];
        float4 v0 = f4[(size_t)s0 * 8 + c];
        float4 v1 = f4[(size_t)s1 * 8 + c];
        a0.x += v0.x; a0.y += v0.y; a0.z += v0.z; a0.w += v0.w;
        a1.x += v1.x; a1.y += v1.y; a1.z += v1.z; a1.w += v1.w;
    }
    if (i < e) {
        int s0 = csrsrc[i];
        float4 v0 = f4[(size_t)s0 * 8 + c];
        a0.x += v0.x; a0.y += v0.y; a0.z += v0.z; a0.w += v0.w;
    }
    a0.x += a1.x; a0.y += a1.y; a0.z += a1.z; a0.w += a1.w;
    reinterpret_cast<float4*>(agg)[(size_t)g * 8 + c] = a0;
}

// ---- post layer1: o = agg/deg + b1 + xr; h1 = tanh(l2norm(o)); fused lin2 ----
__global__ __launch_bounds__(256) void post1_kernel(
    const float* __restrict__ agg, const int* __restrict__ deg,
    const float* __restrict__ xr, const float* __restrict__ b1,
    const float* __restrict__ W2l, const float* __restrict__ W2r,
    float* __restrict__ hl, float* __restrict__ hr)
{
    int node = blockIdx.x * 256 + threadIdx.x;
    if (node >= NN) return;
    float inv = 1.0f / fmaxf((float)deg[node], 1.0f);
    float o[DH];
    const float4* ag4 = reinterpret_cast<const float4*>(agg + (size_t)node * DH);
    const float4* xr4 = reinterpret_cast<const float4*>(xr  + (size_t)node * DH);
#pragma unroll
    for (int q = 0; q < DH / 4; ++q) {
        float4 a = ag4[q]; float4 r = xr4[q];
        o[q*4+0] = fmaf(a.x, inv, b1[q*4+0] + r.x);
        o[q*4+1] = fmaf(a.y, inv, b1[q*4+1] + r.y);
        o[q*4+2] = fmaf(a.z, inv, b1[q*4+2] + r.z);
        o[q*4+3] = fmaf(a.w, inv, b1[q*4+3] + r.w);
    }
    float ss = 0.f;
#pragma unroll
    for (int j = 0; j < DH; ++j) ss += o[j] * o[j];
    float rn = 1.0f / fmaxf(sqrtf(ss), 1e-12f);
    float h[DH];
#pragma unroll
    for (int j = 0; j < DH; ++j) h[j] = tanhf(o[j] * rn);

    float al[DH], ar[DH];
#pragma unroll
    for (int j = 0; j < DH; ++j) { al[j] = 0.f; ar[j] = 0.f; }
    for (int k = 0; k < DH; ++k) {
        float hk = h[k];
        const float* wl = W2l + k * DH;
        const float* wr = W2r + k * DH;
#pragma unroll
        for (int j = 0; j < DH; ++j) {
            al[j] = fmaf(hk, wl[j], al[j]);
            ar[j] = fmaf(hk, wr[j], ar[j]);
        }
    }
    float4* hl4 = reinterpret_cast<float4*>(hl + (size_t)node * DH);
    float4* hr4 = reinterpret_cast<float4*>(hr + (size_t)node * DH);
#pragma unroll
    for (int q = 0; q < DH / 4; ++q) {
        hl4[q] = make_float4(al[q*4+0], al[q*4+1], al[q*4+2], al[q*4+3]);
        hr4[q] = make_float4(ar[q*4+0], ar[q*4+1], ar[q*4+2], ar[q*4+3]);
    }
}

// ---- post layer2 + classifier ----
__global__ __launch_bounds__(256) void post2_kernel(
    const float* __restrict__ agg, const int* __restrict__ deg,
    const float* __restrict__ hr, const float* __restrict__ b2,
    const float* __restrict__ Wc, const float* __restrict__ bc,
    float* __restrict__ h2out, float* __restrict__ outp)
{
    int node = blockIdx.x * 256 + threadIdx.x;
    if (node >= NN) return;
    float inv = 1.0f / fmaxf((float)deg[node], 1.0f);
    float o[DH];
    const float4* ag4 = reinterpret_cast<const float4*>(agg + (size_t)node * DH);
    const float4* hr4 = reinterpret_cast<const float4*>(hr  + (size_t)node * DH);
#pragma unroll
    for (int q = 0; q < DH / 4; ++q) {
        float4 a = ag4[q]; float4 r = hr4[q];
        o[q*4+0] = fmaf(a.x, inv, b2[q*4+0] + r.x);
        o[q*4+1] = fmaf(a.y, inv, b2[q*4+1] + r.y);
        o[q*4+2] = fmaf(a.z, inv, b2[q*4+2] + r.z);
        o[q*4+3] = fmaf(a.w, inv, b2[q*4+3] + r.w);
    }
    float ss = 0.f;
#pragma unroll
    for (int j = 0; j < DH; ++j) ss += o[j] * o[j];
    float rn = 1.0f / fmaxf(sqrtf(ss), 1e-12f);
    float h[DH];
#pragma unroll
    for (int j = 0; j < DH; ++j) h[j] = tanhf(o[j] * rn);

    float4* h2o = reinterpret_cast<float4*>(h2out + (size_t)node * DH);
#pragma unroll
    for (int q = 0; q < DH / 4; ++q)
        h2o[q] = make_float4(h[q*4+0], h[q*4+1], h[q*4+2], h[q*4+3]);

    float z[DOUT];
#pragma unroll
    for (int t = 0; t < DOUT; ++t) z[t] = bc[t];
    for (int k = 0; k < DH; ++k) {
        float hk = h[k];
        const float* wc = Wc + k * DOUT;
#pragma unroll
        for (int t = 0; t < DOUT; ++t) z[t] = fmaf(hk, wc[t], z[t]);
    }
    float m = -INFINITY;
#pragma unroll
    for (int t = 0; t < DOUT; ++t) m = fmaxf(m, z[t]);
    float s = 0.f;
#pragma unroll
    for (int t = 0; t < DOUT; ++t) s += expf(z[t] - m);
    float lse = m + logf(s);
    float* orow = outp + (size_t)node * DOUT;
#pragma unroll
    for (int t = 0; t < DOUT; ++t) orow[t] = z[t] - lse;
}

extern "C" void kernel_launch(void* const* d_in, const int* in_sizes, int n_in,
                              void* d_out, int out_size, void* d_ws, size_t ws_size,
                              hipStream_t stream) {
    const float* x   = (const float*)d_in[0];
    const int*   ei  = (const int*)d_in[1];
    const float* W1l = (const float*)d_in[2];
    const float* b1  = (const float*)d_in[3];
    const float* W1r = (const float*)d_in[4];
    const float* W2l = (const float*)d_in[5];
    const float* b2  = (const float*)d_in[6];
    const float* W2r = (const float*)d_in[7];
    const float* Wc  = (const float*)d_in[8];
    const float* bc  = (const float*)d_in[9];

    float* outp = (float*)d_out;                          // [NN, 20]
    float* hout = outp + (size_t)NN * DOUT;               // [NN, 32]

    // workspace layout
    float* xl   = (float*)d_ws;                           // NN*DH
    float* xr   = xl + (size_t)NN * DH;                   // NN*DH
    float* agg  = xr + (size_t)NN * DH;                   // NN*DH
    int* deg    = (int*)(agg + (size_t)NN * DH);          // NN
    int* start  = deg + NN;                               // NN
    int* ptr    = start + NN;                             // NN
    int* chunkSums = ptr + NN;                            // N_CHUNKS
    int* chunkOffs = chunkSums + N_CHUNKS;                // N_CHUNKS
    int* csrsrc = chunkOffs + N_CHUNKS;                   // NE

    const int nodeBlocks  = (NN + 255) / 256;
    const int edgeBlocks  = (NE + 255) / 256;
    const int quadBlocks  = (NE / 4 + 255) / 256;
    const int groupBlocks = (NN * 8 + 255) / 256;

    hipMemsetAsync(deg, 0, (size_t)NN * sizeof(int), stream);

    lin1_kernel<<<nodeBlocks, 256, 0, stream>>>(x, W1l, W1r, xl, xr);
    hist_kernel<<<edgeBlocks, 256, 0, stream>>>(ei, deg);
    scan_partial<<<N_CHUNKS, SCAN_THREADS, 0, stream>>>(deg, chunkSums);
    scan_offsets<<<1, 64, 0, stream>>>(chunkSums, chunkOffs);
    scan_final<<<N_CHUNKS, SCAN_THREADS, 0, stream>>>(deg, chunkOffs, start, ptr);

    for (int p = 0; p < N_PASSES; ++p) {
        int lo = p * PASS_RANGE;
        int hi = (p + 1 == N_PASSES) ? NN : lo + PASS_RANGE;
        scatter_pass_kernel<<<quadBlocks, 256, 0, stream>>>(ei, ptr, csrsrc, lo, hi);
    }

    gather_kernel<<<groupBlocks, 256, 0, stream>>>(start, deg, csrsrc, xl, agg);
    post1_kernel<<<nodeBlocks, 256, 0, stream>>>(agg, deg, xr, b1, W2l, W2r, xl, xr);

    gather_kernel<<<groupBlocks, 256, 0, stream>>>(start, deg, csrsrc, xl, agg);
    post2_kernel<<<nodeBlocks, 256, 0, stream>>>(agg, deg, xr, b2, Wc, bc, hout, outp);
}

// Round 4
// 285.760 us; speedup vs baseline: 9.9106x; 1.9226x over previous
//
#include <hip/hip_runtime.h>
#include <cmath>

constexpr int NN   = 100000;
constexpr int NE   = 3200000;
constexpr int DIN  = 128;
constexpr int DH   = 32;
constexpr int DOUT = 20;

constexpr int NB    = 392;                 // coarse buckets: dst>>8 -> 0..390 (+1 pad)
constexpr int NBUSE = (NN + 255) / 256;    // 391 buckets actually used
constexpr int NBLK  = 256;                 // phase A/C blocks
constexpr int SLICE = NE / NBLK;           // 12500 edges per block (exact)

// ---------------- layer-1 projections: xl = x@W1l, xr = x@W1r ----------------
__global__ __launch_bounds__(256) void lin1_kernel(
    const float* __restrict__ x, const float* __restrict__ Wl,
    const float* __restrict__ Wr, float* __restrict__ xl, float* __restrict__ xr)
{
    int node = blockIdx.x * 256 + threadIdx.x;
    if (node >= NN) return;
    float accl[DH], accr[DH];
#pragma unroll
    for (int j = 0; j < DH; ++j) { accl[j] = 0.f; accr[j] = 0.f; }
    const float4* xrow = reinterpret_cast<const float4*>(x + (size_t)node * DIN);
    for (int k0 = 0; k0 < DIN; k0 += 4) {
        float4 xv = xrow[k0 >> 2];
        float xs[4] = {xv.x, xv.y, xv.z, xv.w};
#pragma unroll
        for (int kk = 0; kk < 4; ++kk) {
            float xk = xs[kk];
            const float* wl = Wl + (k0 + kk) * DH;
            const float* wr = Wr + (k0 + kk) * DH;
#pragma unroll
            for (int j = 0; j < DH; ++j) {
                accl[j] = fmaf(xk, wl[j], accl[j]);
                accr[j] = fmaf(xk, wr[j], accr[j]);
            }
        }
    }
    float4* xl4 = reinterpret_cast<float4*>(xl + (size_t)node * DH);
    float4* xr4 = reinterpret_cast<float4*>(xr + (size_t)node * DH);
#pragma unroll
    for (int q = 0; q < DH / 4; ++q) {
        xl4[q] = make_float4(accl[q*4+0], accl[q*4+1], accl[q*4+2], accl[q*4+3]);
        xr4[q] = make_float4(accr[q*4+0], accr[q*4+1], accr[q*4+2], accr[q*4+3]);
    }
}

// ---------------- phase A: per-block coarse-bucket histogram (LDS atomics only) -------
__global__ __launch_bounds__(256) void countA_kernel(
    const int* __restrict__ ei, int* __restrict__ counts)
{
    __shared__ int h[NB];
    int blk = blockIdx.x, t = threadIdx.x;
    for (int i = t; i < NB; i += 256) h[i] = 0;
    __syncthreads();
    int base = blk * SLICE;
    for (int i = base + t; i < base + SLICE; i += 256) {
        int dst = ei[NE + i];
        atomicAdd(&h[dst >> 8], 1);
    }
    __syncthreads();
    for (int i = t; i < NB; i += 256) counts[blk * NB + i] = h[i];
}

// ------- phase B1: per-bucket exclusive scan over 256 block counts -------
__global__ __launch_bounds__(256) void scanB1_kernel(
    const int* __restrict__ counts, int* __restrict__ offs, int* __restrict__ totals)
{
    __shared__ int sdata[256];
    int b = blockIdx.x, t = threadIdx.x;
    int v = counts[t * NB + b];
    sdata[t] = v;
    __syncthreads();
    for (int off = 1; off < 256; off <<= 1) {
        int tmp = (t >= off) ? sdata[t - off] : 0;
        __syncthreads();
        sdata[t] += tmp;
        __syncthreads();
    }
    offs[b * 256 + t] = sdata[t] - v;       // exclusive prefix of block t within bucket b
    if (t == 255) totals[b] = sdata[255];
}

// ------- phase B2: exclusive scan of bucket totals (tiny) -------
__global__ void scanB2_kernel(const int* __restrict__ totals, int* __restrict__ bases)
{
    if (threadIdx.x == 0 && blockIdx.x == 0) {
        int acc = 0;
        for (int i = 0; i < NB; ++i) { bases[i] = acc; acc += totals[i]; }
        bases[NB] = acc;
    }
}

// ------- phase C: rank-based scatter into per-(block,bucket) private regions -------
__global__ __launch_bounds__(256) void scatterC_kernel(
    const int* __restrict__ ei, const int* __restrict__ offs,
    const int* __restrict__ bases, unsigned* __restrict__ csrtmp)
{
    __shared__ int cnt[NB];
    __shared__ int wbase[NB];
    int blk = blockIdx.x, t = threadIdx.x;
    for (int i = t; i < NB; i += 256) {
        cnt[i] = 0;
        wbase[i] = bases[i] + offs[i * 256 + blk];
    }
    __syncthreads();
    int base = blk * SLICE;
    for (int i = base + t; i < base + SLICE; i += 256) {
        int dst = ei[NE + i];
        int src = ei[i];
        int b = dst >> 8;
        int r = atomicAdd(&cnt[b], 1);                       // LDS atomic
        csrtmp[wbase[b] + r] = ((unsigned)(dst & 255) << 17) | (unsigned)src;
    }
}

// ------- phase D: regroup within bucket -> final CSR + start + deg -------
__global__ __launch_bounds__(256) void regroupD_kernel(
    const unsigned* __restrict__ csrtmp, const int* __restrict__ bases,
    int* __restrict__ csrsrc, int* __restrict__ deg, int* __restrict__ start)
{
    __shared__ int h[256];
    __shared__ int sdata[256];
    int b = blockIdx.x, t = threadIdx.x;
    int lo = bases[b], hi = bases[b + 1];
    h[t] = 0;
    __syncthreads();
    for (int i = lo + t; i < hi; i += 256)
        atomicAdd(&h[csrtmp[i] >> 17], 1);
    __syncthreads();
    int v = h[t];
    sdata[t] = v;
    __syncthreads();
    for (int off = 1; off < 256; off <<= 1) {
        int tmp = (t >= off) ? sdata[t - off] : 0;
        __syncthreads();
        sdata[t] += tmp;
        __syncthreads();
    }
    int ex = sdata[t] - v;                   // exclusive prefix within bucket
    int node = b * 256 + t;
    if (node < NN) { start[node] = lo + ex; deg[node] = v; }
    h[t] = ex;                               // reuse as running write pointer
    __syncthreads();
    for (int i = lo + t; i < hi; i += 256) {
        unsigned u = csrtmp[i];
        int r = atomicAdd(&h[u >> 17], 1);   // LDS atomic
        csrsrc[lo + r] = (int)(u & 0x1FFFFu);
    }
}

// ---------------- gather aggregation: agg[g] = sum over neighbors ----------------
__global__ __launch_bounds__(256) void gather_kernel(
    const int* __restrict__ start, const int* __restrict__ deg,
    const int* __restrict__ csrsrc, const float* __restrict__ feat,
    float* __restrict__ agg)
{
    int tid = blockIdx.x * 256 + threadIdx.x;
    int g = tid >> 3;            // node
    int c = tid & 7;             // float4 chunk of the 32-dim row
    if (g >= NN) return;
    int s = start[g];
    int e = s + deg[g];
    const float4* f4 = reinterpret_cast<const float4*>(feat);
    float4 a0 = make_float4(0.f, 0.f, 0.f, 0.f);
    float4 a1 = make_float4(0.f, 0.f, 0.f, 0.f);
    int i = s;
    for (; i + 2 <= e; i += 2) {
        int s0 = csrsrc[i];
        int s1 = csrsrc[i + 1];
        float4 v0 = f4[(size_t)s0 * 8 + c];
        float4 v1 = f4[(size_t)s1 * 8 + c];
        a0.x += v0.x; a0.y += v0.y; a0.z += v0.z; a0.w += v0.w;
        a1.x += v1.x; a1.y += v1.y; a1.z += v1.z; a1.w += v1.w;
    }
    if (i < e) {
        int s0 = csrsrc[i];
        float4 v0 = f4[(size_t)s0 * 8 + c];
        a0.x += v0.x; a0.y += v0.y; a0.z += v0.z; a0.w += v0.w;
    }
    a0.x += a1.x; a0.y += a1.y; a0.z += a1.z; a0.w += a1.w;
    reinterpret_cast<float4*>(agg)[(size_t)g * 8 + c] = a0;
}

// ---- post layer1: o = agg/deg + b1 + xr; h1 = tanh(l2norm(o)); fused lin2 ----
__global__ __launch_bounds__(256) void post1_kernel(
    const float* __restrict__ agg, const int* __restrict__ deg,
    const float* __restrict__ xr, const float* __restrict__ b1,
    const float* __restrict__ W2l, const float* __restrict__ W2r,
    float* __restrict__ hl, float* __restrict__ hr)
{
    int node = blockIdx.x * 256 + threadIdx.x;
    if (node >= NN) return;
    float inv = 1.0f / fmaxf((float)deg[node], 1.0f);
    float o[DH];
    const float4* ag4 = reinterpret_cast<const float4*>(agg + (size_t)node * DH);
    const float4* xr4 = reinterpret_cast<const float4*>(xr  + (size_t)node * DH);
#pragma unroll
    for (int q = 0; q < DH / 4; ++q) {
        float4 a = ag4[q]; float4 r = xr4[q];
        o[q*4+0] = fmaf(a.x, inv, b1[q*4+0] + r.x);
        o[q*4+1] = fmaf(a.y, inv, b1[q*4+1] + r.y);
        o[q*4+2] = fmaf(a.z, inv, b1[q*4+2] + r.z);
        o[q*4+3] = fmaf(a.w, inv, b1[q*4+3] + r.w);
    }
    float ss = 0.f;
#pragma unroll
    for (int j = 0; j < DH; ++j) ss += o[j] * o[j];
    float rn = 1.0f / fmaxf(sqrtf(ss), 1e-12f);
    float h[DH];
#pragma unroll
    for (int j = 0; j < DH; ++j) h[j] = tanhf(o[j] * rn);

    float al[DH], ar[DH];
#pragma unroll
    for (int j = 0; j < DH; ++j) { al[j] = 0.f; ar[j] = 0.f; }
    for (int k = 0; k < DH; ++k) {
        float hk = h[k];
        const float* wl = W2l + k * DH;
        const float* wr = W2r + k * DH;
#pragma unroll
        for (int j = 0; j < DH; ++j) {
            al[j] = fmaf(hk, wl[j], al[j]);
            ar[j] = fmaf(hk, wr[j], ar[j]);
        }
    }
    float4* hl4 = reinterpret_cast<float4*>(hl + (size_t)node * DH);
    float4* hr4 = reinterpret_cast<float4*>(hr + (size_t)node * DH);
#pragma unroll
    for (int q = 0; q < DH / 4; ++q) {
        hl4[q] = make_float4(al[q*4+0], al[q*4+1], al[q*4+2], al[q*4+3]);
        hr4[q] = make_float4(ar[q*4+0], ar[q*4+1], ar[q*4+2], ar[q*4+3]);
    }
}

// ---- post layer2 + classifier ----
__global__ __launch_bounds__(256) void post2_kernel(
    const float* __restrict__ agg, const int* __restrict__ deg,
    const float* __restrict__ hr, const float* __restrict__ b2,
    const float* __restrict__ Wc, const float* __restrict__ bc,
    float* __restrict__ h2out, float* __restrict__ outp)
{
    int node = blockIdx.x * 256 + threadIdx.x;
    if (node >= NN) return;
    float inv = 1.0f / fmaxf((float)deg[node], 1.0f);
    float o[DH];
    const float4* ag4 = reinterpret_cast<const float4*>(agg + (size_t)node * DH);
    const float4* hr4 = reinterpret_cast<const float4*>(hr  + (size_t)node * DH);
#pragma unroll
    for (int q = 0; q < DH / 4; ++q) {
        float4 a = ag4[q]; float4 r = hr4[q];
        o[q*4+0] = fmaf(a.x, inv, b2[q*4+0] + r.x);
        o[q*4+1] = fmaf(a.y, inv, b2[q*4+1] + r.y);
        o[q*4+2] = fmaf(a.z, inv, b2[q*4+2] + r.z);
        o[q*4+3] = fmaf(a.w, inv, b2[q*4+3] + r.w);
    }
    float ss = 0.f;
#pragma unroll
    for (int j = 0; j < DH; ++j) ss += o[j] * o[j];
    float rn = 1.0f / fmaxf(sqrtf(ss), 1e-12f);
    float h[DH];
#pragma unroll
    for (int j = 0; j < DH; ++j) h[j] = tanhf(o[j] * rn);

    float4* h2o = reinterpret_cast<float4*>(h2out + (size_t)node * DH);
#pragma unroll
    for (int q = 0; q < DH / 4; ++q)
        h2o[q] = make_float4(h[q*4+0], h[q*4+1], h[q*4+2], h[q*4+3]);

    float z[DOUT];
#pragma unroll
    for (int t = 0; t < DOUT; ++t) z[t] = bc[t];
    for (int k = 0; k < DH; ++k) {
        float hk = h[k];
        const float* wc = Wc + k * DOUT;
#pragma unroll
        for (int t = 0; t < DOUT; ++t) z[t] = fmaf(hk, wc[t], z[t]);
    }
    float m = -INFINITY;
#pragma unroll
    for (int t = 0; t < DOUT; ++t) m = fmaxf(m, z[t]);
    float s = 0.f;
#pragma unroll
    for (int t = 0; t < DOUT; ++t) s += expf(z[t] - m);
    float lse = m + logf(s);
    float* orow = outp + (size_t)node * DOUT;
#pragma unroll
    for (int t = 0; t < DOUT; ++t) orow[t] = z[t] - lse;
}

extern "C" void kernel_launch(void* const* d_in, const int* in_sizes, int n_in,
                              void* d_out, int out_size, void* d_ws, size_t ws_size,
                              hipStream_t stream) {
    const float* x   = (const float*)d_in[0];
    const int*   ei  = (const int*)d_in[1];
    const float* W1l = (const float*)d_in[2];
    const float* b1  = (const float*)d_in[3];
    const float* W1r = (const float*)d_in[4];
    const float* W2l = (const float*)d_in[5];
    const float* b2  = (const float*)d_in[6];
    const float* W2r = (const float*)d_in[7];
    const float* Wc  = (const float*)d_in[8];
    const float* bc  = (const float*)d_in[9];

    float* outp = (float*)d_out;                          // [NN, 20]
    float* hout = outp + (size_t)NN * DOUT;               // [NN, 32]

    // workspace layout (note: csrtmp and agg alias — csrtmp dead before gather runs)
    float* xl      = (float*)d_ws;                        // NN*DH f32
    float* xr      = xl + (size_t)NN * DH;                // NN*DH f32
    float* agg     = xr + (size_t)NN * DH;                // NN*DH f32  (== NE u32)
    unsigned* csrtmp = (unsigned*)agg;                    // NE u32 (aliases agg)
    int* csrsrc    = (int*)(agg + (size_t)NN * DH);       // NE
    int* deg       = csrsrc + NE;                         // NN
    int* start     = deg + NN;                            // NN
    int* counts    = start + NN;                          // NBLK*NB
    int* offs      = counts + NBLK * NB;                  // NB*NBLK
    int* totals    = offs + NB * NBLK;                    // NB
    int* bases     = totals + NB;                         // NB+1

    const int nodeBlocks  = (NN + 255) / 256;
    const int groupBlocks = (NN * 8 + 255) / 256;

    lin1_kernel<<<nodeBlocks, 256, 0, stream>>>(x, W1l, W1r, xl, xr);

    countA_kernel<<<NBLK, 256, 0, stream>>>(ei, counts);
    scanB1_kernel<<<NB, 256, 0, stream>>>(counts, offs, totals);
    scanB2_kernel<<<1, 64, 0, stream>>>(totals, bases);
    scatterC_kernel<<<NBLK, 256, 0, stream>>>(ei, offs, bases, csrtmp);
    regroupD_kernel<<<NBUSE, 256, 0, stream>>>(csrtmp, bases, csrsrc, deg, start);

    gather_kernel<<<groupBlocks, 256, 0, stream>>>(start, deg, csrsrc, xl, agg);
    post1_kernel<<<nodeBlocks, 256, 0, stream>>>(agg, deg, xr, b1, W2l, W2r, xl, xr);

    gather_kernel<<<groupBlocks, 256, 0, stream>>>(start, deg, csrsrc, xl, agg);
    post2_kernel<<<nodeBlocks, 256, 0, stream>>>(agg, deg, xr, b2, Wc, bc, hout, outp);
}

// Round 5
// 268.929 us; speedup vs baseline: 10.5308x; 1.0626x over previous
//
#include <hip/hip_runtime.h>
#include <cmath>

constexpr int NN   = 100000;
constexpr int NE   = 3200000;
constexpr int DIN  = 128;
constexpr int DH   = 32;
constexpr int DOUT = 20;

constexpr int NB    = 392;                 // coarse buckets: dst>>8 -> 0..390 (+1 pad)
constexpr int NBUSE = (NN + 255) / 256;    // 391 buckets actually used
constexpr int NBLK  = 256;                 // phase A/C blocks
constexpr int SLICE = NE / NBLK;           // 12500 edges per block (exact)

constexpr int NPB = 64;                    // nodes per lin1 block
constexpr int XS  = 129;                   // padded LDS row stride (banks: (lane+k)%32)

// ---------------- layer-1 projections: xl = x@W1l, xr = x@W1r ----------------
// 256 threads = 4 waves; block stages 64 x-rows in LDS; wave w computes one
// (matrix, j-half) slice for all 64 nodes (lane == node). W address is
// wave-uniform -> scalar-load friendly.
__global__ __launch_bounds__(256) void lin1_kernel(
    const float* __restrict__ x, const float* __restrict__ Wl,
    const float* __restrict__ Wr, float* __restrict__ xl, float* __restrict__ xr)
{
    __shared__ float xs[NPB * XS];         // 33024 B -> 4 blocks/CU
    int t = threadIdx.x;
    int nodeBase = blockIdx.x * NPB;

    const float4* x4 = reinterpret_cast<const float4*>(x) + (size_t)nodeBase * (DIN / 4);
    for (int i = t; i < NPB * (DIN / 4); i += 256) {
        int n = i >> 5, c = i & 31;
        float4 v = make_float4(0.f, 0.f, 0.f, 0.f);
        if (nodeBase + n < NN) v = x4[i];
        float* p = &xs[n * XS + c * 4];
        p[0] = v.x; p[1] = v.y; p[2] = v.z; p[3] = v.w;
    }
    __syncthreads();

    int wv   = __builtin_amdgcn_readfirstlane(t >> 6);   // 0..3, wave-uniform
    int lane = t & 63;
    int node = nodeBase + lane;
    const float* W = (wv & 2) ? Wr : Wl;
    int jbase = (wv & 1) * 16;

    float acc[16];
#pragma unroll
    for (int j = 0; j < 16; ++j) acc[j] = 0.f;

    const float* xrow = &xs[lane * XS];
    for (int k = 0; k < DIN; ++k) {
        float xv = xrow[k];
        const float4* w4 = reinterpret_cast<const float4*>(W + k * DH + jbase);
#pragma unroll
        for (int q = 0; q < 4; ++q) {
            float4 w = w4[q];
            acc[q*4+0] = fmaf(xv, w.x, acc[q*4+0]);
            acc[q*4+1] = fmaf(xv, w.y, acc[q*4+1]);
            acc[q*4+2] = fmaf(xv, w.z, acc[q*4+2]);
            acc[q*4+3] = fmaf(xv, w.w, acc[q*4+3]);
        }
    }
    if (node < NN) {
        float* op = ((wv & 2) ? xr : xl) + (size_t)node * DH + jbase;
        float4* o4 = reinterpret_cast<float4*>(op);
#pragma unroll
        for (int q = 0; q < 4; ++q)
            o4[q] = make_float4(acc[q*4+0], acc[q*4+1], acc[q*4+2], acc[q*4+3]);
    }
}

// ---------------- phase A: per-block coarse-bucket histogram (LDS atomics only) -------
__global__ __launch_bounds__(256) void countA_kernel(
    const int* __restrict__ ei, int* __restrict__ counts)
{
    __shared__ int h[NB];
    int blk = blockIdx.x, t = threadIdx.x;
    for (int i = t; i < NB; i += 256) h[i] = 0;
    __syncthreads();
    int base = blk * SLICE;
    for (int i = base + t; i < base + SLICE; i += 256) {
        int dst = ei[NE + i];
        atomicAdd(&h[dst >> 8], 1);
    }
    __syncthreads();
    for (int i = t; i < NB; i += 256) counts[blk * NB + i] = h[i];
}

// ------- phase B1: per-bucket exclusive scan over 256 block counts -------
__global__ __launch_bounds__(256) void scanB1_kernel(
    const int* __restrict__ counts, int* __restrict__ offs, int* __restrict__ totals)
{
    __shared__ int sdata[256];
    int b = blockIdx.x, t = threadIdx.x;
    int v = counts[t * NB + b];
    sdata[t] = v;
    __syncthreads();
    for (int off = 1; off < 256; off <<= 1) {
        int tmp = (t >= off) ? sdata[t - off] : 0;
        __syncthreads();
        sdata[t] += tmp;
        __syncthreads();
    }
    offs[b * 256 + t] = sdata[t] - v;
    if (t == 255) totals[b] = sdata[255];
}

// ------- phase B2: exclusive scan of bucket totals (tiny) -------
__global__ void scanB2_kernel(const int* __restrict__ totals, int* __restrict__ bases)
{
    if (threadIdx.x == 0 && blockIdx.x == 0) {
        int acc = 0;
        for (int i = 0; i < NB; ++i) { bases[i] = acc; acc += totals[i]; }
        bases[NB] = acc;
    }
}

// ------- phase C: rank-based scatter into per-(block,bucket) private regions -------
__global__ __launch_bounds__(256) void scatterC_kernel(
    const int* __restrict__ ei, const int* __restrict__ offs,
    const int* __restrict__ bases, unsigned* __restrict__ csrtmp)
{
    __shared__ int cnt[NB];
    __shared__ int wbase[NB];
    int blk = blockIdx.x, t = threadIdx.x;
    for (int i = t; i < NB; i += 256) {
        cnt[i] = 0;
        wbase[i] = bases[i] + offs[i * 256 + blk];
    }
    __syncthreads();
    int base = blk * SLICE;
    for (int i = base + t; i < base + SLICE; i += 256) {
        int dst = ei[NE + i];
        int src = ei[i];
        int b = dst >> 8;
        int r = atomicAdd(&cnt[b], 1);                       // LDS atomic
        csrtmp[wbase[b] + r] = ((unsigned)(dst & 255) << 17) | (unsigned)src;
    }
}

// ------- phase D: regroup within bucket -> final CSR + start + deg -------
__global__ __launch_bounds__(256) void regroupD_kernel(
    const unsigned* __restrict__ csrtmp, const int* __restrict__ bases,
    int* __restrict__ csrsrc, int* __restrict__ deg, int* __restrict__ start)
{
    __shared__ int h[256];
    __shared__ int sdata[256];
    int b = blockIdx.x, t = threadIdx.x;
    int lo = bases[b], hi = bases[b + 1];
    h[t] = 0;
    __syncthreads();
    for (int i = lo + t; i < hi; i += 256)
        atomicAdd(&h[csrtmp[i] >> 17], 1);
    __syncthreads();
    int v = h[t];
    sdata[t] = v;
    __syncthreads();
    for (int off = 1; off < 256; off <<= 1) {
        int tmp = (t >= off) ? sdata[t - off] : 0;
        __syncthreads();
        sdata[t] += tmp;
        __syncthreads();
    }
    int ex = sdata[t] - v;
    int node = b * 256 + t;
    if (node < NN) { start[node] = lo + ex; deg[node] = v; }
    h[t] = ex;
    __syncthreads();
    for (int i = lo + t; i < hi; i += 256) {
        unsigned u = csrtmp[i];
        int r = atomicAdd(&h[u >> 17], 1);   // LDS atomic
        csrsrc[lo + r] = (int)(u & 0x1FFFFu);
    }
}

// ---------------- gather aggregation: agg[g] = sum over neighbors ----------------
__global__ __launch_bounds__(256) void gather_kernel(
    const int* __restrict__ start, const int* __restrict__ deg,
    const int* __restrict__ csrsrc, const float* __restrict__ feat,
    float* __restrict__ agg)
{
    int tid = blockIdx.x * 256 + threadIdx.x;
    int g = tid >> 3;            // node
    int c = tid & 7;             // float4 chunk of the 32-dim row
    if (g >= NN) return;
    int s = start[g];
    int e = s + deg[g];
    const float4* f4 = reinterpret_cast<const float4*>(feat);
    float4 a0 = make_float4(0.f, 0.f, 0.f, 0.f);
    float4 a1 = make_float4(0.f, 0.f, 0.f, 0.f);
    int i = s;
    for (; i + 2 <= e; i += 2) {
        int s0 = csrsrc[i];
        int s1 = csrsrc[i + 1];
        float4 v0 = f4[(size_t)s0 * 8 + c];
        float4 v1 = f4[(size_t)s1 * 8 + c];
        a0.x += v0.x; a0.y += v0.y; a0.z += v0.z; a0.w += v0.w;
        a1.x += v1.x; a1.y += v1.y; a1.z += v1.z; a1.w += v1.w;
    }
    if (i < e) {
        int s0 = csrsrc[i];
        float4 v0 = f4[(size_t)s0 * 8 + c];
        a0.x += v0.x; a0.y += v0.y; a0.z += v0.z; a0.w += v0.w;
    }
    a0.x += a1.x; a0.y += a1.y; a0.z += a1.z; a0.w += a1.w;
    reinterpret_cast<float4*>(agg)[(size_t)g * 8 + c] = a0;
}

// ---- post layer1: o = agg/deg + b1 + xr; h1 = tanh(l2norm(o)); fused lin2 ----
__global__ __launch_bounds__(256) void post1_kernel(
    const float* __restrict__ agg, const int* __restrict__ deg,
    const float* __restrict__ xr, const float* __restrict__ b1,
    const float* __restrict__ W2l, const float* __restrict__ W2r,
    float* __restrict__ hl, float* __restrict__ hr)
{
    int node = blockIdx.x * 256 + threadIdx.x;
    if (node >= NN) return;
    float inv = 1.0f / fmaxf((float)deg[node], 1.0f);
    float o[DH];
    const float4* ag4 = reinterpret_cast<const float4*>(agg + (size_t)node * DH);
    const float4* xr4 = reinterpret_cast<const float4*>(xr  + (size_t)node * DH);
#pragma unroll
    for (int q = 0; q < DH / 4; ++q) {
        float4 a = ag4[q]; float4 r = xr4[q];
        o[q*4+0] = fmaf(a.x, inv, b1[q*4+0] + r.x);
        o[q*4+1] = fmaf(a.y, inv, b1[q*4+1] + r.y);
        o[q*4+2] = fmaf(a.z, inv, b1[q*4+2] + r.z);
        o[q*4+3] = fmaf(a.w, inv, b1[q*4+3] + r.w);
    }
    float ss = 0.f;
#pragma unroll
    for (int j = 0; j < DH; ++j) ss += o[j] * o[j];
    float rn = 1.0f / fmaxf(sqrtf(ss), 1e-12f);
    float h[DH];
#pragma unroll
    for (int j = 0; j < DH; ++j) h[j] = tanhf(o[j] * rn);

    float al[DH], ar[DH];
#pragma unroll
    for (int j = 0; j < DH; ++j) { al[j] = 0.f; ar[j] = 0.f; }
    for (int k = 0; k < DH; ++k) {
        float hk = h[k];
        const float* wl = W2l + k * DH;
        const float* wr = W2r + k * DH;
#pragma unroll
        for (int j = 0; j < DH; ++j) {
            al[j] = fmaf(hk, wl[j], al[j]);
            ar[j] = fmaf(hk, wr[j], ar[j]);
        }
    }
    float4* hl4 = reinterpret_cast<float4*>(hl + (size_t)node * DH);
    float4* hr4 = reinterpret_cast<float4*>(hr + (size_t)node * DH);
#pragma unroll
    for (int q = 0; q < DH / 4; ++q) {
        hl4[q] = make_float4(al[q*4+0], al[q*4+1], al[q*4+2], al[q*4+3]);
        hr4[q] = make_float4(ar[q*4+0], ar[q*4+1], ar[q*4+2], ar[q*4+3]);
    }
}

// ---- post layer2 + classifier ----
__global__ __launch_bounds__(256) void post2_kernel(
    const float* __restrict__ agg, const int* __restrict__ deg,
    const float* __restrict__ hr, const float* __restrict__ b2,
    const float* __restrict__ Wc, const float* __restrict__ bc,
    float* __restrict__ h2out, float* __restrict__ outp)
{
    int node = blockIdx.x * 256 + threadIdx.x;
    if (node >= NN) return;
    float inv = 1.0f / fmaxf((float)deg[node], 1.0f);
    float o[DH];
    const float4* ag4 = reinterpret_cast<const float4*>(agg + (size_t)node * DH);
    const float4* hr4 = reinterpret_cast<const float4*>(hr  + (size_t)node * DH);
#pragma unroll
    for (int q = 0; q < DH / 4; ++q) {
        float4 a = ag4[q]; float4 r = hr4[q];
        o[q*4+0] = fmaf(a.x, inv, b2[q*4+0] + r.x);
        o[q*4+1] = fmaf(a.y, inv, b2[q*4+1] + r.y);
        o[q*4+2] = fmaf(a.z, inv, b2[q*4+2] + r.z);
        o[q*4+3] = fmaf(a.w, inv, b2[q*4+3] + r.w);
    }
    float ss = 0.f;
#pragma unroll
    for (int j = 0; j < DH; ++j) ss += o[j] * o[j];
    float rn = 1.0f / fmaxf(sqrtf(ss), 1e-12f);
    float h[DH];
#pragma unroll
    for (int j = 0; j < DH; ++j) h[j] = tanhf(o[j] * rn);

    float4* h2o = reinterpret_cast<float4*>(h2out + (size_t)node * DH);
#pragma unroll
    for (int q = 0; q < DH / 4; ++q)
        h2o[q] = make_float4(h[q*4+0], h[q*4+1], h[q*4+2], h[q*4+3]);

    float z[DOUT];
#pragma unroll
    for (int t = 0; t < DOUT; ++t) z[t] = bc[t];
    for (int k = 0; k < DH; ++k) {
        float hk = h[k];
        const float* wc = Wc + k * DOUT;
#pragma unroll
        for (int t = 0; t < DOUT; ++t) z[t] = fmaf(hk, wc[t], z[t]);
    }
    float m = -INFINITY;
#pragma unroll
    for (int t = 0; t < DOUT; ++t) m = fmaxf(m, z[t]);
    float s = 0.f;
#pragma unroll
    for (int t = 0; t < DOUT; ++t) s += expf(z[t] - m);
    float lse = m + logf(s);
    float* orow = outp + (size_t)node * DOUT;
#pragma unroll
    for (int t = 0; t < DOUT; ++t) orow[t] = z[t] - lse;
}

extern "C" void kernel_launch(void* const* d_in, const int* in_sizes, int n_in,
                              void* d_out, int out_size, void* d_ws, size_t ws_size,
                              hipStream_t stream) {
    const float* x   = (const float*)d_in[0];
    const int*   ei  = (const int*)d_in[1];
    const float* W1l = (const float*)d_in[2];
    const float* b1  = (const float*)d_in[3];
    const float* W1r = (const float*)d_in[4];
    const float* W2l = (const float*)d_in[5];
    const float* b2  = (const float*)d_in[6];
    const float* W2r = (const float*)d_in[7];
    const float* Wc  = (const float*)d_in[8];
    const float* bc  = (const float*)d_in[9];

    float* outp = (float*)d_out;                          // [NN, 20]
    float* hout = outp + (size_t)NN * DOUT;               // [NN, 32]

    // workspace layout (note: csrtmp and agg alias — csrtmp dead before gather runs)
    float* xl      = (float*)d_ws;                        // NN*DH f32
    float* xr      = xl + (size_t)NN * DH;                // NN*DH f32
    float* agg     = xr + (size_t)NN * DH;                // NN*DH f32  (== NE u32)
    unsigned* csrtmp = (unsigned*)agg;                    // NE u32 (aliases agg)
    int* csrsrc    = (int*)(agg + (size_t)NN * DH);       // NE
    int* deg       = csrsrc + NE;                         // NN
    int* start     = deg + NN;                            // NN
    int* counts    = start + NN;                          // NBLK*NB
    int* offs      = counts + NBLK * NB;                  // NB*NBLK
    int* totals    = offs + NB * NBLK;                    // NB
    int* bases     = totals + NB;                         // NB+1

    const int nodeBlocks  = (NN + 255) / 256;
    const int lin1Blocks  = (NN + NPB - 1) / NPB;         // 1563
    const int groupBlocks = (NN * 8 + 255) / 256;

    lin1_kernel<<<lin1Blocks, 256, 0, stream>>>(x, W1l, W1r, xl, xr);

    countA_kernel<<<NBLK, 256, 0, stream>>>(ei, counts);
    scanB1_kernel<<<NB, 256, 0, stream>>>(counts, offs, totals);
    scanB2_kernel<<<1, 64, 0, stream>>>(totals, bases);
    scatterC_kernel<<<NBLK, 256, 0, stream>>>(ei, offs, bases, csrtmp);
    regroupD_kernel<<<NBUSE, 256, 0, stream>>>(csrtmp, bases, csrsrc, deg, start);

    gather_kernel<<<groupBlocks, 256, 0, stream>>>(start, deg, csrsrc, xl, agg);
    post1_kernel<<<nodeBlocks, 256, 0, stream>>>(agg, deg, xr, b1, W2l, W2r, xl, xr);

    gather_kernel<<<groupBlocks, 256, 0, stream>>>(start, deg, csrsrc, xl, agg);
    post2_kernel<<<nodeBlocks, 256, 0, stream>>>(agg, deg, xr, b2, Wc, bc, hout, outp);
}

// Round 6
// 260.987 us; speedup vs baseline: 10.8513x; 1.0304x over previous
//
#include <hip/hip_runtime.h>
#include <cmath>

constexpr int NN   = 100000;
constexpr int NE   = 3200000;
constexpr int DIN  = 128;
constexpr int DH   = 32;
constexpr int DOUT = 20;

constexpr int NB    = 392;                 // coarse buckets: dst>>8 -> 0..390 (+1 pad)
constexpr int NBUSE = (NN + 255) / 256;    // 391 buckets actually used
constexpr int NBLK  = 256;                 // phase A/C blocks
constexpr int SLICE = NE / NBLK;           // 12500 edges per block (exact)

constexpr int NPB = 64;                    // nodes per lin1 block
constexpr int XS  = 129;                   // padded LDS row stride

__device__ inline unsigned short f2bf(float f) {           // RNE float->bf16
    unsigned u = __builtin_bit_cast(unsigned, f);
    unsigned r = 0x7FFFu + ((u >> 16) & 1u);
    return (unsigned short)((u + r) >> 16);
}
__device__ inline float bflo(unsigned u) {                 // low ushort -> float
    return __builtin_bit_cast(float, u << 16);
}
__device__ inline float bfhi(unsigned u) {                 // high ushort -> float
    return __builtin_bit_cast(float, u & 0xFFFF0000u);
}

// ---------------- layer-1 projections: xl(bf16) = x@W1l, xr(f32) = x@W1r ----------------
__global__ __launch_bounds__(256) void lin1_kernel(
    const float* __restrict__ x, const float* __restrict__ Wl,
    const float* __restrict__ Wr, unsigned short* __restrict__ xlbf,
    float* __restrict__ xr)
{
    __shared__ float xs[NPB * XS];
    int t = threadIdx.x;
    int nodeBase = blockIdx.x * NPB;

    const float4* x4 = reinterpret_cast<const float4*>(x) + (size_t)nodeBase * (DIN / 4);
    for (int i = t; i < NPB * (DIN / 4); i += 256) {
        int n = i >> 5, c = i & 31;
        float4 v = make_float4(0.f, 0.f, 0.f, 0.f);
        if (nodeBase + n < NN) v = x4[i];
        float* p = &xs[n * XS + c * 4];
        p[0] = v.x; p[1] = v.y; p[2] = v.z; p[3] = v.w;
    }
    __syncthreads();

    int wv   = __builtin_amdgcn_readfirstlane(t >> 6);   // 0..3
    int lane = t & 63;
    int node = nodeBase + lane;
    const float* W = (wv & 2) ? Wr : Wl;
    int jbase = (wv & 1) * 16;

    float acc[16];
#pragma unroll
    for (int j = 0; j < 16; ++j) acc[j] = 0.f;

    const float* xrow = &xs[lane * XS];
    for (int k = 0; k < DIN; ++k) {
        float xv = xrow[k];
        const float4* w4 = reinterpret_cast<const float4*>(W + k * DH + jbase);
#pragma unroll
        for (int q = 0; q < 4; ++q) {
            float4 w = w4[q];
            acc[q*4+0] = fmaf(xv, w.x, acc[q*4+0]);
            acc[q*4+1] = fmaf(xv, w.y, acc[q*4+1]);
            acc[q*4+2] = fmaf(xv, w.z, acc[q*4+2]);
            acc[q*4+3] = fmaf(xv, w.w, acc[q*4+3]);
        }
    }
    if (node < NN) {
        if (wv & 2) {
            float4* o4 = reinterpret_cast<float4*>(xr + (size_t)node * DH + jbase);
#pragma unroll
            for (int q = 0; q < 4; ++q)
                o4[q] = make_float4(acc[q*4+0], acc[q*4+1], acc[q*4+2], acc[q*4+3]);
        } else {
            unsigned pk[8];
#pragma unroll
            for (int q = 0; q < 8; ++q)
                pk[q] = (unsigned)f2bf(acc[q*2]) | ((unsigned)f2bf(acc[q*2+1]) << 16);
            uint4* o4 = reinterpret_cast<uint4*>(xlbf + (size_t)node * DH + jbase);
            o4[0] = make_uint4(pk[0], pk[1], pk[2], pk[3]);
            o4[1] = make_uint4(pk[4], pk[5], pk[6], pk[7]);
        }
    }
}

// ---------------- phase A: per-block coarse-bucket histogram ----------------
__global__ __launch_bounds__(256) void countA_kernel(
    const int* __restrict__ ei, int* __restrict__ counts)
{
    __shared__ int h[NB];
    int blk = blockIdx.x, t = threadIdx.x;
    for (int i = t; i < NB; i += 256) h[i] = 0;
    __syncthreads();
    int base = blk * SLICE;
    for (int i = base + t; i < base + SLICE; i += 256) {
        int dst = ei[NE + i];
        atomicAdd(&h[dst >> 8], 1);
    }
    __syncthreads();
    for (int i = t; i < NB; i += 256) counts[blk * NB + i] = h[i];
}

// ------- phase B1: per-bucket exclusive scan over 256 block counts -------
__global__ __launch_bounds__(256) void scanB1_kernel(
    const int* __restrict__ counts, int* __restrict__ offs, int* __restrict__ totals)
{
    __shared__ int sdata[256];
    int b = blockIdx.x, t = threadIdx.x;
    int v = counts[t * NB + b];
    sdata[t] = v;
    __syncthreads();
    for (int off = 1; off < 256; off <<= 1) {
        int tmp = (t >= off) ? sdata[t - off] : 0;
        __syncthreads();
        sdata[t] += tmp;
        __syncthreads();
    }
    offs[b * 256 + t] = sdata[t] - v;
    if (t == 255) totals[b] = sdata[255];
}

// ------- phase B2: exclusive scan of bucket totals (tiny) -------
__global__ void scanB2_kernel(const int* __restrict__ totals, int* __restrict__ bases)
{
    if (threadIdx.x == 0 && blockIdx.x == 0) {
        int acc = 0;
        for (int i = 0; i < NB; ++i) { bases[i] = acc; acc += totals[i]; }
        bases[NB] = acc;
    }
}

// ------- phase C: rank-based scatter into per-(block,bucket) private regions -------
__global__ __launch_bounds__(256) void scatterC_kernel(
    const int* __restrict__ ei, const int* __restrict__ offs,
    const int* __restrict__ bases, unsigned* __restrict__ csrtmp)
{
    __shared__ int cnt[NB];
    __shared__ int wbase[NB];
    int blk = blockIdx.x, t = threadIdx.x;
    for (int i = t; i < NB; i += 256) {
        cnt[i] = 0;
        wbase[i] = bases[i] + offs[i * 256 + blk];
    }
    __syncthreads();
    int base = blk * SLICE;
    for (int i = base + t; i < base + SLICE; i += 256) {
        int dst = ei[NE + i];
        int src = ei[i];
        int b = dst >> 8;
        int r = atomicAdd(&cnt[b], 1);                       // LDS atomic
        csrtmp[wbase[b] + r] = ((unsigned)(dst & 255) << 17) | (unsigned)src;
    }
}

// ------- phase D: regroup within bucket -> final CSR + start + deg -------
__global__ __launch_bounds__(256) void regroupD_kernel(
    const unsigned* __restrict__ csrtmp, const int* __restrict__ bases,
    int* __restrict__ csrsrc, int* __restrict__ deg, int* __restrict__ start)
{
    __shared__ int h[256];
    __shared__ int sdata[256];
    int b = blockIdx.x, t = threadIdx.x;
    int lo = bases[b], hi = bases[b + 1];
    h[t] = 0;
    __syncthreads();
    for (int i = lo + t; i < hi; i += 256)
        atomicAdd(&h[csrtmp[i] >> 17], 1);
    __syncthreads();
    int v = h[t];
    sdata[t] = v;
    __syncthreads();
    for (int off = 1; off < 256; off <<= 1) {
        int tmp = (t >= off) ? sdata[t - off] : 0;
        __syncthreads();
        sdata[t] += tmp;
        __syncthreads();
    }
    int ex = sdata[t] - v;
    int node = b * 256 + t;
    if (node < NN) { start[node] = lo + ex; deg[node] = v; }
    h[t] = ex;
    __syncthreads();
    for (int i = lo + t; i < hi; i += 256) {
        unsigned u = csrtmp[i];
        int r = atomicAdd(&h[u >> 17], 1);   // LDS atomic
        csrsrc[lo + r] = (int)(u & 0x1FFFFu);
    }
}

// ------- gather (bf16 feat rows, 64 B/row): agg[g] = sum over neighbors -------
__global__ __launch_bounds__(256) void gather_kernel(
    const int* __restrict__ start, const int* __restrict__ deg,
    const int* __restrict__ csrsrc, const unsigned short* __restrict__ feat,
    float* __restrict__ agg)
{
    int tid = blockIdx.x * 256 + threadIdx.x;
    int g = tid >> 3;            // node
    int c = tid & 7;             // uint2 chunk (4 bf16) of the 32-dim row
    if (g >= NN) return;
    int s = start[g];
    int e = s + deg[g];
    const uint2* f2 = reinterpret_cast<const uint2*>(feat);
    float4 a0 = make_float4(0.f, 0.f, 0.f, 0.f);
    float4 a1 = make_float4(0.f, 0.f, 0.f, 0.f);
    int i = s;
    for (; i + 2 <= e; i += 2) {
        int s0 = csrsrc[i];
        int s1 = csrsrc[i + 1];
        uint2 v0 = f2[(size_t)s0 * 8 + c];
        uint2 v1 = f2[(size_t)s1 * 8 + c];
        a0.x += bflo(v0.x); a0.y += bfhi(v0.x); a0.z += bflo(v0.y); a0.w += bfhi(v0.y);
        a1.x += bflo(v1.x); a1.y += bfhi(v1.x); a1.z += bflo(v1.y); a1.w += bfhi(v1.y);
    }
    if (i < e) {
        int s0 = csrsrc[i];
        uint2 v0 = f2[(size_t)s0 * 8 + c];
        a0.x += bflo(v0.x); a0.y += bfhi(v0.x); a0.z += bflo(v0.y); a0.w += bfhi(v0.y);
    }
    a0.x += a1.x; a0.y += a1.y; a0.z += a1.z; a0.w += a1.w;
    reinterpret_cast<float4*>(agg)[(size_t)g * 8 + c] = a0;
}

// ---- post layer1: o = agg/deg + b1 + xr; h1 = tanh(l2norm(o));
//      hl(bf16) = h1@W2l, hr(f32) = h1@W2r ----
__global__ __launch_bounds__(256) void post1_kernel(
    const float* __restrict__ agg, const int* __restrict__ deg,
    const float* __restrict__ xr, const float* __restrict__ b1,
    const float* __restrict__ W2l, const float* __restrict__ W2r,
    unsigned short* __restrict__ hlbf, float* __restrict__ hr)
{
    int node = blockIdx.x * 256 + threadIdx.x;
    if (node >= NN) return;
    float inv = 1.0f / fmaxf((float)deg[node], 1.0f);
    float o[DH];
    const float4* ag4 = reinterpret_cast<const float4*>(agg + (size_t)node * DH);
    const float4* xr4 = reinterpret_cast<const float4*>(xr  + (size_t)node * DH);
#pragma unroll
    for (int q = 0; q < DH / 4; ++q) {
        float4 a = ag4[q]; float4 r = xr4[q];
        o[q*4+0] = fmaf(a.x, inv, b1[q*4+0] + r.x);
        o[q*4+1] = fmaf(a.y, inv, b1[q*4+1] + r.y);
        o[q*4+2] = fmaf(a.z, inv, b1[q*4+2] + r.z);
        o[q*4+3] = fmaf(a.w, inv, b1[q*4+3] + r.w);
    }
    float ss = 0.f;
#pragma unroll
    for (int j = 0; j < DH; ++j) ss += o[j] * o[j];
    float rn = 1.0f / fmaxf(sqrtf(ss), 1e-12f);
    float h[DH];
#pragma unroll
    for (int j = 0; j < DH; ++j) h[j] = tanhf(o[j] * rn);

    float al[DH], ar[DH];
#pragma unroll
    for (int j = 0; j < DH; ++j) { al[j] = 0.f; ar[j] = 0.f; }
    for (int k = 0; k < DH; ++k) {
        float hk = h[k];
        const float* wl = W2l + k * DH;
        const float* wr = W2r + k * DH;
#pragma unroll
        for (int j = 0; j < DH; ++j) {
            al[j] = fmaf(hk, wl[j], al[j]);
            ar[j] = fmaf(hk, wr[j], ar[j]);
        }
    }
    unsigned pk[16];
#pragma unroll
    for (int q = 0; q < 16; ++q)
        pk[q] = (unsigned)f2bf(al[q*2]) | ((unsigned)f2bf(al[q*2+1]) << 16);
    uint4* hl4 = reinterpret_cast<uint4*>(hlbf + (size_t)node * DH);
    hl4[0] = make_uint4(pk[0],  pk[1],  pk[2],  pk[3]);
    hl4[1] = make_uint4(pk[4],  pk[5],  pk[6],  pk[7]);
    hl4[2] = make_uint4(pk[8],  pk[9],  pk[10], pk[11]);
    hl4[3] = make_uint4(pk[12], pk[13], pk[14], pk[15]);
    float4* hr4 = reinterpret_cast<float4*>(hr + (size_t)node * DH);
#pragma unroll
    for (int q = 0; q < DH / 4; ++q)
        hr4[q] = make_float4(ar[q*4+0], ar[q*4+1], ar[q*4+2], ar[q*4+3]);
}

// ---- post layer2 + classifier ----
__global__ __launch_bounds__(256) void post2_kernel(
    const float* __restrict__ agg, const int* __restrict__ deg,
    const float* __restrict__ hr, const float* __restrict__ b2,
    const float* __restrict__ Wc, const float* __restrict__ bc,
    float* __restrict__ h2out, float* __restrict__ outp)
{
    int node = blockIdx.x * 256 + threadIdx.x;
    if (node >= NN) return;
    float inv = 1.0f / fmaxf((float)deg[node], 1.0f);
    float o[DH];
    const float4* ag4 = reinterpret_cast<const float4*>(agg + (size_t)node * DH);
    const float4* hr4 = reinterpret_cast<const float4*>(hr  + (size_t)node * DH);
#pragma unroll
    for (int q = 0; q < DH / 4; ++q) {
        float4 a = ag4[q]; float4 r = hr4[q];
        o[q*4+0] = fmaf(a.x, inv, b2[q*4+0] + r.x);
        o[q*4+1] = fmaf(a.y, inv, b2[q*4+1] + r.y);
        o[q*4+2] = fmaf(a.z, inv, b2[q*4+2] + r.z);
        o[q*4+3] = fmaf(a.w, inv, b2[q*4+3] + r.w);
    }
    float ss = 0.f;
#pragma unroll
    for (int j = 0; j < DH; ++j) ss += o[j] * o[j];
    float rn = 1.0f / fmaxf(sqrtf(ss), 1e-12f);
    float h[DH];
#pragma unroll
    for (int j = 0; j < DH; ++j) h[j] = tanhf(o[j] * rn);

    float4* h2o = reinterpret_cast<float4*>(h2out + (size_t)node * DH);
#pragma unroll
    for (int q = 0; q < DH / 4; ++q)
        h2o[q] = make_float4(h[q*4+0], h[q*4+1], h[q*4+2], h[q*4+3]);

    float z[DOUT];
#pragma unroll
    for (int t = 0; t < DOUT; ++t) z[t] = bc[t];
    for (int k = 0; k < DH; ++k) {
        float hk = h[k];
        const float* wc = Wc + k * DOUT;
#pragma unroll
        for (int t = 0; t < DOUT; ++t) z[t] = fmaf(hk, wc[t], z[t]);
    }
    float m = -INFINITY;
#pragma unroll
    for (int t = 0; t < DOUT; ++t) m = fmaxf(m, z[t]);
    float s = 0.f;
#pragma unroll
    for (int t = 0; t < DOUT; ++t) s += expf(z[t] - m);
    float lse = m + logf(s);
    float* orow = outp + (size_t)node * DOUT;
#pragma unroll
    for (int t = 0; t < DOUT; ++t) orow[t] = z[t] - lse;
}

extern "C" void kernel_launch(void* const* d_in, const int* in_sizes, int n_in,
                              void* d_out, int out_size, void* d_ws, size_t ws_size,
                              hipStream_t stream) {
    const float* x   = (const float*)d_in[0];
    const int*   ei  = (const int*)d_in[1];
    const float* W1l = (const float*)d_in[2];
    const float* b1  = (const float*)d_in[3];
    const float* W1r = (const float*)d_in[4];
    const float* W2l = (const float*)d_in[5];
    const float* b2  = (const float*)d_in[6];
    const float* W2r = (const float*)d_in[7];
    const float* Wc  = (const float*)d_in[8];
    const float* bc  = (const float*)d_in[9];

    float* outp = (float*)d_out;                          // [NN, 20]
    float* hout = outp + (size_t)NN * DOUT;               // [NN, 32]

    // workspace layout
    // xlbf: bf16 features for gather (layer1 = xl, layer2 = hl; sequential reuse)
    unsigned short* xlbf = (unsigned short*)d_ws;         // NN*DH bf16 (6.4 MB)
    float* xr      = (float*)(xlbf + (size_t)NN * DH);    // NN*DH f32 (also hr, thread-local RAW)
    float* agg     = xr + (size_t)NN * DH;                // NN*DH f32 (== NE u32, aliases csrtmp)
    unsigned* csrtmp = (unsigned*)agg;                    // NE u32
    int* csrsrc    = (int*)(agg + (size_t)NN * DH);       // NE
    int* deg       = csrsrc + NE;                         // NN
    int* start     = deg + NN;                            // NN
    int* counts    = start + NN;                          // NBLK*NB
    int* offs      = counts + NBLK * NB;                  // NB*NBLK
    int* totals    = offs + NB * NBLK;                    // NB
    int* bases     = totals + NB;                         // NB+1

    const int nodeBlocks  = (NN + 255) / 256;
    const int lin1Blocks  = (NN + NPB - 1) / NPB;
    const int groupBlocks = (NN * 8 + 255) / 256;

    lin1_kernel<<<lin1Blocks, 256, 0, stream>>>(x, W1l, W1r, xlbf, xr);

    countA_kernel<<<NBLK, 256, 0, stream>>>(ei, counts);
    scanB1_kernel<<<NB, 256, 0, stream>>>(counts, offs, totals);
    scanB2_kernel<<<1, 64, 0, stream>>>(totals, bases);
    scatterC_kernel<<<NBLK, 256, 0, stream>>>(ei, offs, bases, csrtmp);
    regroupD_kernel<<<NBUSE, 256, 0, stream>>>(csrtmp, bases, csrsrc, deg, start);

    gather_kernel<<<groupBlocks, 256, 0, stream>>>(start, deg, csrsrc, xlbf, agg);
    post1_kernel<<<nodeBlocks, 256, 0, stream>>>(agg, deg, xr, b1, W2l, W2r, xlbf, xr);

    gather_kernel<<<groupBlocks, 256, 0, stream>>>(start, deg, csrsrc, xlbf, agg);
    post2_kernel<<<nodeBlocks, 256, 0, stream>>>(agg, deg, xr, b2, Wc, bc, hout, outp);
}

// Round 7
// 259.317 us; speedup vs baseline: 10.9212x; 1.0064x over previous
//
#include <hip/hip_runtime.h>
#include <cmath>

constexpr int NN   = 100000;
constexpr int NE   = 3200000;
constexpr int DIN  = 128;
constexpr int DH   = 32;
constexpr int DOUT = 20;

constexpr int NB    = 392;                 // coarse buckets: dst>>8 -> 0..390 (+1 pad)
constexpr int NBUSE = (NN + 255) / 256;    // 391 buckets actually used
constexpr int NBLK  = 256;                 // phase A/C blocks
constexpr int SLICE = NE / NBLK;           // 12500 edges per block (exact)

constexpr int NPB = 64;                    // nodes per lin1 block
constexpr int XS  = 132;                   // padded LDS row stride (float4-aligned, 2-way banks)

__device__ inline unsigned short f2bf(float f) {           // RNE float->bf16
    unsigned u = __builtin_bit_cast(unsigned, f);
    unsigned r = 0x7FFFu + ((u >> 16) & 1u);
    return (unsigned short)((u + r) >> 16);
}
__device__ inline float bflo(unsigned u) {                 // low ushort -> float
    return __builtin_bit_cast(float, u << 16);
}
__device__ inline float bfhi(unsigned u) {                 // high ushort -> float
    return __builtin_bit_cast(float, u & 0xFFFF0000u);
}

// ---------------- layer-1 projections: xl(bf16) = x@W1l, xr(f32) = x@W1r ----------------
__global__ __launch_bounds__(256) void lin1_kernel(
    const float* __restrict__ x, const float* __restrict__ Wl,
    const float* __restrict__ Wr, unsigned short* __restrict__ xlbf,
    float* __restrict__ xr)
{
    __shared__ float xs[NPB * XS];         // 33792 B -> 4 blocks/CU
    int t = threadIdx.x;
    int nodeBase = blockIdx.x * NPB;

    const float4* x4 = reinterpret_cast<const float4*>(x) + (size_t)nodeBase * (DIN / 4);
    for (int i = t; i < NPB * (DIN / 4); i += 256) {
        int n = i >> 5, c = i & 31;
        float4 v = make_float4(0.f, 0.f, 0.f, 0.f);
        if (nodeBase + n < NN) v = x4[i];
        *reinterpret_cast<float4*>(&xs[n * XS + c * 4]) = v;   // b128, aligned
    }
    __syncthreads();

    int wv   = __builtin_amdgcn_readfirstlane(t >> 6);   // 0..3
    int lane = t & 63;
    int node = nodeBase + lane;
    const float* W = (wv & 2) ? Wr : Wl;
    int jbase = (wv & 1) * 16;

    float acc[16];
#pragma unroll
    for (int j = 0; j < 16; ++j) acc[j] = 0.f;

    const float* xrow = &xs[lane * XS];
    for (int k0 = 0; k0 < DIN; k0 += 8) {
        float4 va = *reinterpret_cast<const float4*>(xrow + k0);
        float4 vb = *reinterpret_cast<const float4*>(xrow + k0 + 4);
        float xv[8] = {va.x, va.y, va.z, va.w, vb.x, vb.y, vb.z, vb.w};
#pragma unroll
        for (int kk = 0; kk < 8; ++kk) {
            float xk = xv[kk];
            const float4* w4 = reinterpret_cast<const float4*>(W + (k0 + kk) * DH + jbase);
#pragma unroll
            for (int q = 0; q < 4; ++q) {
                float4 w = w4[q];
                acc[q*4+0] = fmaf(xk, w.x, acc[q*4+0]);
                acc[q*4+1] = fmaf(xk, w.y, acc[q*4+1]);
                acc[q*4+2] = fmaf(xk, w.z, acc[q*4+2]);
                acc[q*4+3] = fmaf(xk, w.w, acc[q*4+3]);
            }
        }
    }
    if (node < NN) {
        if (wv & 2) {
            float4* o4 = reinterpret_cast<float4*>(xr + (size_t)node * DH + jbase);
#pragma unroll
            for (int q = 0; q < 4; ++q)
                o4[q] = make_float4(acc[q*4+0], acc[q*4+1], acc[q*4+2], acc[q*4+3]);
        } else {
            unsigned pk[8];
#pragma unroll
            for (int q = 0; q < 8; ++q)
                pk[q] = (unsigned)f2bf(acc[q*2]) | ((unsigned)f2bf(acc[q*2+1]) << 16);
            uint4* o4 = reinterpret_cast<uint4*>(xlbf + (size_t)node * DH + jbase);
            o4[0] = make_uint4(pk[0], pk[1], pk[2], pk[3]);
            o4[1] = make_uint4(pk[4], pk[5], pk[6], pk[7]);
        }
    }
}

// ---------------- phase A: per-block coarse-bucket histogram ----------------
__global__ __launch_bounds__(256) void countA_kernel(
    const int* __restrict__ ei, int* __restrict__ counts)
{
    __shared__ int h[NB];
    int blk = blockIdx.x, t = threadIdx.x;
    for (int i = t; i < NB; i += 256) h[i] = 0;
    __syncthreads();
    int base = blk * SLICE;
    for (int i = base + t; i < base + SLICE; i += 256) {
        int dst = ei[NE + i];
        atomicAdd(&h[dst >> 8], 1);
    }
    __syncthreads();
    for (int i = t; i < NB; i += 256) counts[blk * NB + i] = h[i];
}

// ------- phase B1: per-bucket exclusive scan over 256 block counts -------
__global__ __launch_bounds__(256) void scanB1_kernel(
    const int* __restrict__ counts, int* __restrict__ offs, int* __restrict__ totals)
{
    __shared__ int sdata[256];
    int b = blockIdx.x, t = threadIdx.x;
    int v = counts[t * NB + b];
    sdata[t] = v;
    __syncthreads();
    for (int off = 1; off < 256; off <<= 1) {
        int tmp = (t >= off) ? sdata[t - off] : 0;
        __syncthreads();
        sdata[t] += tmp;
        __syncthreads();
    }
    offs[b * 256 + t] = sdata[t] - v;
    if (t == 255) totals[b] = sdata[255];
}

// ------- phase B2: exclusive scan of bucket totals (tiny) -------
__global__ void scanB2_kernel(const int* __restrict__ totals, int* __restrict__ bases)
{
    if (threadIdx.x == 0 && blockIdx.x == 0) {
        int acc = 0;
        for (int i = 0; i < NB; ++i) { bases[i] = acc; acc += totals[i]; }
        bases[NB] = acc;
    }
}

// ------- phase C: rank-based scatter into per-(block,bucket) private regions -------
__global__ __launch_bounds__(256) void scatterC_kernel(
    const int* __restrict__ ei, const int* __restrict__ offs,
    const int* __restrict__ bases, unsigned* __restrict__ csrtmp)
{
    __shared__ int cnt[NB];
    __shared__ int wbase[NB];
    int blk = blockIdx.x, t = threadIdx.x;
    for (int i = t; i < NB; i += 256) {
        cnt[i] = 0;
        wbase[i] = bases[i] + offs[i * 256 + blk];
    }
    __syncthreads();
    int base = blk * SLICE;
    for (int i = base + t; i < base + SLICE; i += 256) {
        int dst = ei[NE + i];
        int src = ei[i];
        int b = dst >> 8;
        int r = atomicAdd(&cnt[b], 1);                       // LDS atomic
        csrtmp[wbase[b] + r] = ((unsigned)(dst & 255) << 17) | (unsigned)src;
    }
}

// ------- phase D: regroup within bucket -> final CSR + start + deg -------
__global__ __launch_bounds__(256) void regroupD_kernel(
    const unsigned* __restrict__ csrtmp, const int* __restrict__ bases,
    int* __restrict__ csrsrc, int* __restrict__ deg, int* __restrict__ start)
{
    __shared__ int h[256];
    __shared__ int sdata[256];
    int b = blockIdx.x, t = threadIdx.x;
    int lo = bases[b], hi = bases[b + 1];
    h[t] = 0;
    __syncthreads();
    for (int i = lo + t; i < hi; i += 256)
        atomicAdd(&h[csrtmp[i] >> 17], 1);
    __syncthreads();
    int v = h[t];
    sdata[t] = v;
    __syncthreads();
    for (int off = 1; off < 256; off <<= 1) {
        int tmp = (t >= off) ? sdata[t - off] : 0;
        __syncthreads();
        sdata[t] += tmp;
        __syncthreads();
    }
    int ex = sdata[t] - v;
    int node = b * 256 + t;
    if (node < NN) { start[node] = lo + ex; deg[node] = v; }
    h[t] = ex;
    __syncthreads();
    for (int i = lo + t; i < hi; i += 256) {
        unsigned u = csrtmp[i];
        int r = atomicAdd(&h[u >> 17], 1);   // LDS atomic
        csrsrc[lo + r] = (int)(u & 0x1FFFFu);
    }
}

// ------- gather (bf16 feat rows, 64 B/row): agg[g] = sum over neighbors -------
__global__ __launch_bounds__(256) void gather_kernel(
    const int* __restrict__ start, const int* __restrict__ deg,
    const int* __restrict__ csrsrc, const unsigned short* __restrict__ feat,
    float* __restrict__ agg)
{
    int tid = blockIdx.x * 256 + threadIdx.x;
    int g = tid >> 3;            // node
    int c = tid & 7;             // uint2 chunk (4 bf16) of the 32-dim row
    if (g >= NN) return;
    int s = start[g];
    int e = s + deg[g];
    const uint2* f2 = reinterpret_cast<const uint2*>(feat);
    float4 a0 = make_float4(0.f, 0.f, 0.f, 0.f);
    float4 a1 = make_float4(0.f, 0.f, 0.f, 0.f);
    int i = s;
    for (; i + 2 <= e; i += 2) {
        int s0 = csrsrc[i];
        int s1 = csrsrc[i + 1];
        uint2 v0 = f2[(size_t)s0 * 8 + c];
        uint2 v1 = f2[(size_t)s1 * 8 + c];
        a0.x += bflo(v0.x); a0.y += bfhi(v0.x); a0.z += bflo(v0.y); a0.w += bfhi(v0.y);
        a1.x += bflo(v1.x); a1.y += bfhi(v1.x); a1.z += bflo(v1.y); a1.w += bfhi(v1.y);
    }
    if (i < e) {
        int s0 = csrsrc[i];
        uint2 v0 = f2[(size_t)s0 * 8 + c];
        a0.x += bflo(v0.x); a0.y += bfhi(v0.x); a0.z += bflo(v0.y); a0.w += bfhi(v0.y);
    }
    a0.x += a1.x; a0.y += a1.y; a0.z += a1.z; a0.w += a1.w;
    reinterpret_cast<float4*>(agg)[(size_t)g * 8 + c] = a0;
}

// ---- post layer1: o = agg/deg + b1 + xr; h1 = tanh(l2norm(o));
//      hl(bf16) = h1@W2l, hr(f32) = h1@W2r ----
__global__ __launch_bounds__(256) void post1_kernel(
    const float* __restrict__ agg, const int* __restrict__ deg,
    const float* __restrict__ xr, const float* __restrict__ b1,
    const float* __restrict__ W2l, const float* __restrict__ W2r,
    unsigned short* __restrict__ hlbf, float* __restrict__ hr)
{
    int node = blockIdx.x * 256 + threadIdx.x;
    if (node >= NN) return;
    float inv = 1.0f / fmaxf((float)deg[node], 1.0f);
    float o[DH];
    const float4* ag4 = reinterpret_cast<const float4*>(agg + (size_t)node * DH);
    const float4* xr4 = reinterpret_cast<const float4*>(xr  + (size_t)node * DH);
#pragma unroll
    for (int q = 0; q < DH / 4; ++q) {
        float4 a = ag4[q]; float4 r = xr4[q];
        o[q*4+0] = fmaf(a.x, inv, b1[q*4+0] + r.x);
        o[q*4+1] = fmaf(a.y, inv, b1[q*4+1] + r.y);
        o[q*4+2] = fmaf(a.z, inv, b1[q*4+2] + r.z);
        o[q*4+3] = fmaf(a.w, inv, b1[q*4+3] + r.w);
    }
    float ss = 0.f;
#pragma unroll
    for (int j = 0; j < DH; ++j) ss += o[j] * o[j];
    float rn = 1.0f / fmaxf(sqrtf(ss), 1e-12f);
    float h[DH];
#pragma unroll
    for (int j = 0; j < DH; ++j) h[j] = tanhf(o[j] * rn);

    float al[DH], ar[DH];
#pragma unroll
    for (int j = 0; j < DH; ++j) { al[j] = 0.f; ar[j] = 0.f; }
    for (int k = 0; k < DH; ++k) {
        float hk = h[k];
        const float* wl = W2l + k * DH;
        const float* wr = W2r + k * DH;
#pragma unroll
        for (int j = 0; j < DH; ++j) {
            al[j] = fmaf(hk, wl[j], al[j]);
            ar[j] = fmaf(hk, wr[j], ar[j]);
        }
    }
    unsigned pk[16];
#pragma unroll
    for (int q = 0; q < 16; ++q)
        pk[q] = (unsigned)f2bf(al[q*2]) | ((unsigned)f2bf(al[q*2+1]) << 16);
    uint4* hl4 = reinterpret_cast<uint4*>(hlbf + (size_t)node * DH);
    hl4[0] = make_uint4(pk[0],  pk[1],  pk[2],  pk[3]);
    hl4[1] = make_uint4(pk[4],  pk[5],  pk[6],  pk[7]);
    hl4[2] = make_uint4(pk[8],  pk[9],  pk[10], pk[11]);
    hl4[3] = make_uint4(pk[12], pk[13], pk[14], pk[15]);
    float4* hr4 = reinterpret_cast<float4*>(hr + (size_t)node * DH);
#pragma unroll
    for (int q = 0; q < DH / 4; ++q)
        hr4[q] = make_float4(ar[q*4+0], ar[q*4+1], ar[q*4+2], ar[q*4+3]);
}

// ---- post layer2 + classifier ----
__global__ __launch_bounds__(256) void post2_kernel(
    const float* __restrict__ agg, const int* __restrict__ deg,
    const float* __restrict__ hr, const float* __restrict__ b2,
    const float* __restrict__ Wc, const float* __restrict__ bc,
    float* __restrict__ h2out, float* __restrict__ outp)
{
    int node = blockIdx.x * 256 + threadIdx.x;
    if (node >= NN) return;
    float inv = 1.0f / fmaxf((float)deg[node], 1.0f);
    float o[DH];
    const float4* ag4 = reinterpret_cast<const float4*>(agg + (size_t)node * DH);
    const float4* hr4 = reinterpret_cast<const float4*>(hr  + (size_t)node * DH);
#pragma unroll
    for (int q = 0; q < DH / 4; ++q) {
        float4 a = ag4[q]; float4 r = hr4[q];
        o[q*4+0] = fmaf(a.x, inv, b2[q*4+0] + r.x);
        o[q*4+1] = fmaf(a.y, inv, b2[q*4+1] + r.y);
        o[q*4+2] = fmaf(a.z, inv, b2[q*4+2] + r.z);
        o[q*4+3] = fmaf(a.w, inv, b2[q*4+3] + r.w);
    }
    float ss = 0.f;
#pragma unroll
    for (int j = 0; j < DH; ++j) ss += o[j] * o[j];
    float rn = 1.0f / fmaxf(sqrtf(ss), 1e-12f);
    float h[DH];
#pragma unroll
    for (int j = 0; j < DH; ++j) h[j] = tanhf(o[j] * rn);

    float4* h2o = reinterpret_cast<float4*>(h2out + (size_t)node * DH);
#pragma unroll
    for (int q = 0; q < DH / 4; ++q)
        h2o[q] = make_float4(h[q*4+0], h[q*4+1], h[q*4+2], h[q*4+3]);

    float z[DOUT];
#pragma unroll
    for (int t = 0; t < DOUT; ++t) z[t] = bc[t];
    for (int k = 0; k < DH; ++k) {
        float hk = h[k];
        const float* wc = Wc + k * DOUT;
#pragma unroll
        for (int t = 0; t < DOUT; ++t) z[t] = fmaf(hk, wc[t], z[t]);
    }
    float m = -INFINITY;
#pragma unroll
    for (int t = 0; t < DOUT; ++t) m = fmaxf(m, z[t]);
    float s = 0.f;
#pragma unroll
    for (int t = 0; t < DOUT; ++t) s += expf(z[t] - m);
    float lse = m + logf(s);
    float* orow = outp + (size_t)node * DOUT;
#pragma unroll
    for (int t = 0; t < DOUT; ++t) orow[t] = z[t] - lse;
}

extern "C" void kernel_launch(void* const* d_in, const int* in_sizes, int n_in,
                              void* d_out, int out_size, void* d_ws, size_t ws_size,
                              hipStream_t stream) {
    const float* x   = (const float*)d_in[0];
    const int*   ei  = (const int*)d_in[1];
    const float* W1l = (const float*)d_in[2];
    const float* b1  = (const float*)d_in[3];
    const float* W1r = (const float*)d_in[4];
    const float* W2l = (const float*)d_in[5];
    const float* b2  = (const float*)d_in[6];
    const float* W2r = (const float*)d_in[7];
    const float* Wc  = (const float*)d_in[8];
    const float* bc  = (const float*)d_in[9];

    float* outp = (float*)d_out;                          // [NN, 20]
    float* hout = outp + (size_t)NN * DOUT;               // [NN, 32]

    // workspace layout
    unsigned short* xlbf = (unsigned short*)d_ws;         // NN*DH bf16 (6.4 MB)
    float* xr      = (float*)(xlbf + (size_t)NN * DH);    // NN*DH f32 (also hr)
    float* agg     = xr + (size_t)NN * DH;                // NN*DH f32 (aliases csrtmp)
    unsigned* csrtmp = (unsigned*)agg;                    // NE u32
    int* csrsrc    = (int*)(agg + (size_t)NN * DH);       // NE
    int* deg       = csrsrc + NE;                         // NN
    int* start     = deg + NN;                            // NN
    int* counts    = start + NN;                          // NBLK*NB
    int* offs      = counts + NBLK * NB;                  // NB*NBLK
    int* totals    = offs + NB * NBLK;                    // NB
    int* bases     = totals + NB;                         // NB+1

    const int nodeBlocks  = (NN + 255) / 256;
    const int lin1Blocks  = (NN + NPB - 1) / NPB;
    const int groupBlocks = (NN * 8 + 255) / 256;

    lin1_kernel<<<lin1Blocks, 256, 0, stream>>>(x, W1l, W1r, xlbf, xr);

    countA_kernel<<<NBLK, 256, 0, stream>>>(ei, counts);
    scanB1_kernel<<<NB, 256, 0, stream>>>(counts, offs, totals);
    scanB2_kernel<<<1, 64, 0, stream>>>(totals, bases);
    scatterC_kernel<<<NBLK, 256, 0, stream>>>(ei, offs, bases, csrtmp);
    regroupD_kernel<<<NBUSE, 256, 0, stream>>>(csrtmp, bases, csrsrc, deg, start);

    gather_kernel<<<groupBlocks, 256, 0, stream>>>(start, deg, csrsrc, xlbf, agg);
    post1_kernel<<<nodeBlocks, 256, 0, stream>>>(agg, deg, xr, b1, W2l, W2r, xlbf, xr);

    gather_kernel<<<groupBlocks, 256, 0, stream>>>(start, deg, csrsrc, xlbf, agg);
    post2_kernel<<<nodeBlocks, 256, 0, stream>>>(agg, deg, xr, b2, Wc, bc, hout, outp);
}